// Round 5
// baseline (796.859 us; speedup 1.0000x reference)
//
#include <hip/hip_runtime.h>
#include <hip/hip_bf16.h>

typedef __hip_bfloat16 bf16;
typedef __attribute__((ext_vector_type(8))) short short8;   // 8 bf16 frag
typedef __attribute__((ext_vector_type(4))) float floatx4;  // MFMA C/D frag

#define HDIM 128
#define NCANON 27

__device__ __forceinline__ float b2f(bf16 v) { return __bfloat162float(v); }
__device__ __forceinline__ float s2f(short s) {
  return __uint_as_float(((unsigned int)(unsigned short)s) << 16);
}

// ------------------------------------------------- dtype detect (bf16 vs f32)
__global__ void detect_kernel(const unsigned short* __restrict__ xraw, int* __restrict__ flag) {
  int j = threadIdx.x;                      // 64 threads
  unsigned short u = xraw[2 * j];
  int e = (u >> 7) & 0xFF;
  int ok = (u == 0) || (e >= 100 && e <= 140);
  unsigned long long m = __ballot(ok);
  if (j == 0) flag[0] = (__popcll(m) >= 48) ? 1 : 0;   // 1 = bf16 storage
}

struct CanonDesc {
  const void* src[NCANON];
  int prefix[NCANON + 1];
};

__global__ void canon_kernel(CanonDesc d, const int* __restrict__ flag,
                             bf16* __restrict__ out, int total) {
  int t = blockIdx.x * 256 + threadIdx.x;
  if (t >= total) return;
  int ti = 0;
  while (d.prefix[ti + 1] <= t) ti++;
  int off = t - d.prefix[ti];
  if (flag[0]) out[t] = ((const bf16*)d.src[ti])[off];
  else         out[t] = __float2bfloat16(((const float*)d.src[ti])[off]);
}

__global__ void emit_kernel(const bf16* __restrict__ canon_out, const int* __restrict__ flag,
                            void* __restrict__ d_out, int n) {
  int t = blockIdx.x * 256 + threadIdx.x;
  if (t >= n) return;
  if (flag[0]) ((bf16*)d_out)[t] = canon_out[t];
  else         ((float*)d_out)[t] = __bfloat162float(canon_out[t]);
}

// ---------------------------------------------------------------- CSR build
__global__ void hist_kernel(const int* __restrict__ dst, int* __restrict__ cnt, int E) {
  int e = blockIdx.x * 256 + threadIdx.x;
  if (e < E) atomicAdd(&cnt[dst[e]], 1);
}

__global__ void scan1_kernel(const int* __restrict__ cnt, int* __restrict__ bsum, int n) {
  int tid = threadIdx.x, lane = tid & 63, wave = tid >> 6;
  int i = blockIdx.x * 256 + tid;
  int v = (i < n) ? cnt[i] : 0;
  #pragma unroll
  for (int d = 32; d; d >>= 1) v += __shfl_down(v, d);
  __shared__ int ws[4];
  if (lane == 0) ws[wave] = v;
  __syncthreads();
  if (tid == 0) bsum[blockIdx.x] = ws[0] + ws[1] + ws[2] + ws[3];
}

__global__ void scan2_kernel(int* __restrict__ bsum, int nb) {   // nb <= 128; 64 threads
  int lane = threadIdx.x;
  int a0 = (lane < nb) ? bsum[lane] : 0;
  int b0 = (64 + lane < nb) ? bsum[64 + lane] : 0;
  int a = a0, b = b0;
  #pragma unroll
  for (int d = 1; d < 64; d <<= 1) { int t = __shfl_up(a, d); if (lane >= d) a += t; }
  int totA = __shfl(a, 63);
  #pragma unroll
  for (int d = 1; d < 64; d <<= 1) { int t = __shfl_up(b, d); if (lane >= d) b += t; }
  int totB = __shfl(b, 63);
  if (lane < nb) bsum[lane] = a - a0;
  if (64 + lane < nb) bsum[64 + lane] = b - b0 + totA;
  if (lane == 0) bsum[nb] = totA + totB;
}

__global__ void scan3_kernel(const int* __restrict__ cnt, const int* __restrict__ bsum,
                             int* __restrict__ row_start, int n, int nb) {
  __shared__ int sh[256];
  int tid = threadIdx.x;
  int i = blockIdx.x * 256 + tid;
  int v = (i < n) ? cnt[i] : 0;
  sh[tid] = v;
  __syncthreads();
  #pragma unroll
  for (int off = 1; off < 256; off <<= 1) {
    int t = (tid >= off) ? sh[tid - off] : 0;
    __syncthreads();
    sh[tid] += t;
    __syncthreads();
  }
  if (i < n) row_start[i] = bsum[blockIdx.x] + sh[tid] - v;
  if (blockIdx.x == 0 && tid == 0) row_start[n] = bsum[nb];
}

__global__ void scatter_kernel(const int* __restrict__ src, const int* __restrict__ dst,
                               const int* __restrict__ row_start, int* __restrict__ cursor,
                               int* __restrict__ sortedE, int* __restrict__ srcS,
                               int* __restrict__ dstS, int E) {
  int e = blockIdx.x * 256 + threadIdx.x;
  if (e < E) {
    int d = dst[e];
    int pos = row_start[d] + atomicAdd(&cursor[d], 1);
    sortedE[pos] = e;
    srcS[pos] = src[e];
    dstS[pos] = d;
  }
}

// ------------------------------------------------- type-sorted node permutation
__global__ void thist_kernel(const int* __restrict__ types, int* __restrict__ tcnt, int n) {
  int i = blockIdx.x * 256 + threadIdx.x;
  if (i < n) atomicAdd(&tcnt[types[i]], 1);
}
__global__ void toff_kernel(const int* __restrict__ tcnt, int* __restrict__ ts) {
  ts[0] = 0; ts[1] = tcnt[0]; ts[2] = tcnt[0] + tcnt[1]; ts[3] = ts[2] + tcnt[2];
}
__global__ void tscatter_kernel(const int* __restrict__ types, const int* __restrict__ ts,
                                int* __restrict__ tcur, int* __restrict__ perm, int n) {
  int i = blockIdx.x * 256 + threadIdx.x;
  if (i < n) {
    int t = types[i];
    int pos = ts[t] + atomicAdd(&tcur[t], 1);
    perm[pos] = i;
  }
}

// ------------------------------------------------------------- aggregation
__global__ void aggregate_kernel(const bf16* __restrict__ h_edges, const int* __restrict__ row_start,
                                 bf16* __restrict__ m_node, int n) {
  int node = blockIdx.x * 4 + (threadIdx.x >> 6);
  if (node >= n) return;
  int lane = threadIdx.x & 63;
  int chunk = lane & 15;
  int sub = lane >> 4;
  int s = row_start[node], e = row_start[node + 1];
  float acc[8];
  #pragma unroll
  for (int j = 0; j < 8; j++) acc[j] = 0.f;
  for (int p = s + sub; p < e; p += 4) {
    short8 v = *(const short8*)(h_edges + (size_t)p * HDIM + chunk * 8);
    #pragma unroll
    for (int j = 0; j < 8; j++) acc[j] += s2f(v[j]);
  }
  #pragma unroll
  for (int j = 0; j < 8; j++) {
    acc[j] += __shfl_xor(acc[j], 16);
    acc[j] += __shfl_xor(acc[j], 32);
  }
  if (sub == 0) {
    short8 o;
    #pragma unroll
    for (int j = 0; j < 8; j++) o[j] = (short)__bfloat16_as_ushort(__float2bfloat16(acc[j]));
    *(short8*)(m_node + (size_t)node * HDIM + chunk * 8) = o;
  }
}

// -------------------------------------------------- fused weight pre-pack (B-frag order)
struct PackJob { const bf16* src; bf16* dst; int Ksrc; int KS; int srcCols; };
struct PackJobs { PackJob j[40]; };

__global__ void pack_all_kernel(PackJobs J) {
  PackJob job = J.j[blockIdx.y];
  int idx = blockIdx.x * 256 + threadIdx.x;
  int total = 8 * job.KS * 64;
  if (idx >= total) return;
  int lane = idx & 63;
  int ks = (idx >> 6) % job.KS;
  int ct = idx / (64 * job.KS);
  bf16* o = job.dst + (size_t)idx * 8;
  int ncol = ct * 16 + (lane & 15);
  int kb = ks * 32 + ((lane >> 4) & 3) * 8;
  #pragma unroll
  for (int jj = 0; jj < 8; jj++) {
    int k = kb + jj;
    o[jj] = (k < job.Ksrc && ncol < job.srcCols)
              ? job.src[(size_t)k * job.srcCols + ncol] : __float2bfloat16(0.f);
  }
}

// -------------------------------------------------- single-GEMM node kernel (Y = X @ W)
__global__ void __launch_bounds__(256) ygemm_kernel(
    const bf16* __restrict__ X,
    const bf16* __restrict__ WpA, const bf16* __restrict__ WpB,
    bf16* __restrict__ outA, bf16* __restrict__ outB, int M) {
  const bf16* Wp = blockIdx.y ? WpB : WpA;
  bf16* outp = blockIdx.y ? outB : outA;
  constexpr int BM = 64, RT = 4, SK = 136;
  __shared__ bf16 Zt[BM * SK];
  const int tid = threadIdx.x;
  const int lane = tid & 63, wave = tid >> 6, colq = lane & 15, quad = lane >> 4;
  const int row0 = blockIdx.x * BM;
  {
    int row = tid >> 2, sub = tid & 3;
    int gr = row0 + row;
    bool ok = gr < M;
    #pragma unroll
    for (int j = 0; j < 4; j++) {
      int seg = j * 4 + sub;
      uint4 v = {0u, 0u, 0u, 0u};
      if (ok) v = *(const uint4*)(X + (size_t)gr * HDIM + seg * 8);
      *(uint4*)(&Zt[row * SK + seg * 8]) = v;
    }
  }
  __syncthreads();
  floatx4 acc[RT][2];
  #pragma unroll
  for (int rt = 0; rt < RT; rt++)
    #pragma unroll
    for (int c = 0; c < 2; c++) acc[rt][c] = (floatx4){0.f, 0.f, 0.f, 0.f};
  #pragma unroll
  for (int ks = 0; ks < 4; ks++) {
    short8 bfr0 = *(const short8*)(Wp + (((size_t)(wave * 2 + 0) * 4 + ks) * 64 + lane) * 8);
    short8 bfr1 = *(const short8*)(Wp + (((size_t)(wave * 2 + 1) * 4 + ks) * 64 + lane) * 8);
    #pragma unroll
    for (int rt = 0; rt < RT; rt++) {
      short8 a = *(const short8*)(&Zt[(rt * 16 + colq) * SK + ks * 32 + quad * 8]);
      acc[rt][0] = __builtin_amdgcn_mfma_f32_16x16x32_bf16(a, bfr0, acc[rt][0], 0, 0, 0);
      acc[rt][1] = __builtin_amdgcn_mfma_f32_16x16x32_bf16(a, bfr1, acc[rt][1], 0, 0, 0);
    }
  }
  #pragma unroll
  for (int c = 0; c < 2; c++) {
    int col = wave * 32 + c * 16 + colq;
    #pragma unroll
    for (int rt = 0; rt < RT; rt++)
      #pragma unroll
      for (int r = 0; r < 4; r++) {
        int grow = row0 + rt * 16 + quad * 4 + r;
        if (grow < M) outp[(size_t)grow * HDIM + col] = __float2bfloat16(acc[rt][c][r]);
      }
  }
}

// -------------------------------------------------- edge-update kernel (ysum trick)
// out = h_e_old + (ReLU(h_e @ W1c + ysum + b1) @ W2 + b2)
// Zt part0 = ysum (becomes Hid in-place, per-lane element ownership), part1 = h_e.
template<int BM>
__global__ void __launch_bounds__(256) eu_kernel(
    const bf16* __restrict__ he, const bf16* __restrict__ ysrc, const bf16* __restrict__ ydst,
    const int* __restrict__ srcS, const int* __restrict__ dstS,
    const bf16* __restrict__ W1p, const bf16* __restrict__ b1v,
    const bf16* __restrict__ W2p, const bf16* __restrict__ b2v,
    bf16* __restrict__ outp, int M) {
  constexpr int RT = BM / 16;
  constexpr int SK = 264;
  __shared__ bf16 Zt[BM * SK];
  const int tid = threadIdx.x;
  const int lane = tid & 63, wave = tid >> 6, colq = lane & 15, quad = lane >> 4;
  const int row0 = blockIdx.x * BM;
  constexpr int TPR = 256 / BM;
  {
    int row = tid / TPR, sub = tid % TPR;
    int gr = row0 + row;
    bool ok = gr < M;
    int g0 = ok ? srcS[gr] : 0;
    int g1 = ok ? dstS[gr] : 0;
    #pragma unroll
    for (int j = 0; j < 32 / TPR; j++) {
      int c = j * TPR + sub;
      int part = c >> 4, seg = c & 15;
      if (part == 0) {
        short8 o = {0, 0, 0, 0, 0, 0, 0, 0};
        if (ok) {
          short8 a = *(const short8*)(ysrc + (size_t)g0 * HDIM + seg * 8);
          short8 b = *(const short8*)(ydst + (size_t)g1 * HDIM + seg * 8);
          #pragma unroll
          for (int k = 0; k < 8; k++)
            o[k] = (short)__bfloat16_as_ushort(__float2bfloat16(s2f(a[k]) + s2f(b[k])));
        }
        *(short8*)(&Zt[row * SK + seg * 8]) = o;
      } else {
        uint4 v = {0u, 0u, 0u, 0u};
        if (ok) v = *(const uint4*)(he + (size_t)gr * HDIM + seg * 8);
        *(uint4*)(&Zt[row * SK + 128 + seg * 8]) = v;
      }
    }
  }
  __syncthreads();

  floatx4 acc[RT][2];
  #pragma unroll
  for (int rt = 0; rt < RT; rt++)
    #pragma unroll
    for (int c = 0; c < 2; c++) acc[rt][c] = (floatx4){0.f, 0.f, 0.f, 0.f};
  #pragma unroll
  for (int ks = 0; ks < 4; ks++) {
    short8 bfr0 = *(const short8*)(W1p + (((size_t)(wave * 2 + 0) * 4 + ks) * 64 + lane) * 8);
    short8 bfr1 = *(const short8*)(W1p + (((size_t)(wave * 2 + 1) * 4 + ks) * 64 + lane) * 8);
    #pragma unroll
    for (int rt = 0; rt < RT; rt++) {
      short8 a = *(const short8*)(&Zt[(rt * 16 + colq) * SK + 128 + ks * 32 + quad * 8]);
      acc[rt][0] = __builtin_amdgcn_mfma_f32_16x16x32_bf16(a, bfr0, acc[rt][0], 0, 0, 0);
      acc[rt][1] = __builtin_amdgcn_mfma_f32_16x16x32_bf16(a, bfr1, acc[rt][1], 0, 0, 0);
    }
  }
  // epilogue: read ysum, write Hid in-place (same addr, same owning lane; part1 untouched)
  #pragma unroll
  for (int c = 0; c < 2; c++) {
    int col = wave * 32 + c * 16 + colq;
    float bv = b2f(b1v[col]);
    #pragma unroll
    for (int rt = 0; rt < RT; rt++)
      #pragma unroll
      for (int r = 0; r < 4; r++) {
        int lrow = rt * 16 + quad * 4 + r;
        float v = acc[rt][c][r] + bv + b2f(Zt[lrow * SK + col]);
        Zt[lrow * SK + col] = __float2bfloat16(fmaxf(v, 0.f));
      }
  }
  __syncthreads();

  floatx4 acc2[RT][2];
  #pragma unroll
  for (int rt = 0; rt < RT; rt++)
    #pragma unroll
    for (int c = 0; c < 2; c++) acc2[rt][c] = (floatx4){0.f, 0.f, 0.f, 0.f};
  #pragma unroll
  for (int ks = 0; ks < 4; ks++) {
    short8 bfr0 = *(const short8*)(W2p + (((size_t)(wave * 2 + 0) * 4 + ks) * 64 + lane) * 8);
    short8 bfr1 = *(const short8*)(W2p + (((size_t)(wave * 2 + 1) * 4 + ks) * 64 + lane) * 8);
    #pragma unroll
    for (int rt = 0; rt < RT; rt++) {
      short8 a = *(const short8*)(&Zt[(rt * 16 + colq) * SK + ks * 32 + quad * 8]);
      acc2[rt][0] = __builtin_amdgcn_mfma_f32_16x16x32_bf16(a, bfr0, acc2[rt][0], 0, 0, 0);
      acc2[rt][1] = __builtin_amdgcn_mfma_f32_16x16x32_bf16(a, bfr1, acc2[rt][1], 0, 0, 0);
    }
  }
  #pragma unroll
  for (int c = 0; c < 2; c++) {
    int col = wave * 32 + c * 16 + colq;
    float bv = b2f(b2v[col]);
    #pragma unroll
    for (int rt = 0; rt < RT; rt++)
      #pragma unroll
      for (int r = 0; r < 4; r++) {
        int lrow = rt * 16 + quad * 4 + r;
        int grow = row0 + lrow;
        if (grow < M) {
          float v = acc2[rt][c][r] + bv + b2f(Zt[lrow * SK + 128 + col]);
          outp[(size_t)grow * HDIM + col] = __float2bfloat16(v);
        }
      }
  }
}

// -------------------------------------------------- typed enc/dec (type-sorted MFMA)
template<int KS1, bool DEC>
__global__ void __launch_bounds__(256) typed_kernel(
    const bf16* __restrict__ in0, const bf16* __restrict__ in1,
    const int* __restrict__ perm, const int* __restrict__ ts,
    const bf16* __restrict__ W1p, int w1s, const bf16* __restrict__ b1v, int b1s,
    const bf16* __restrict__ W2p, int w2s, const bf16* __restrict__ b2v, int b2s,
    bf16* __restrict__ outp) {
  constexpr int BM = 64, RT = 4;
  constexpr int SK = KS1 * 32 + 8;
  constexpr int HS = 136;
  int t = blockIdx.y;
  int rs = ts[t], re = ts[t + 1];
  int row0 = rs + blockIdx.x * BM;
  if (row0 >= re) return;
  __shared__ bf16 Zt[BM * SK];
  __shared__ bf16 Hid[BM * HS];
  __shared__ int gIdx[BM];
  const int tid = threadIdx.x;
  const int lane = tid & 63, wave = tid >> 6, colq = lane & 15, quad = lane >> 4;
  for (int i = tid; i < BM; i += 256) gIdx[i] = (row0 + i < re) ? perm[row0 + i] : -1;
  __syncthreads();
  if (DEC) {
    int row = tid >> 2, sub = tid & 3;
    int g = gIdx[row];
    #pragma unroll
    for (int j = 0; j < 4; j++) {
      int seg = j * 4 + sub;
      uint4 v = {0u, 0u, 0u, 0u};
      if (g >= 0) v = *(const uint4*)(in0 + (size_t)g * HDIM + seg * 8);
      *(uint4*)(&Zt[row * SK + seg * 8]) = v;
    }
  } else {
    for (int i = tid; i < BM * 32; i += 256) {
      int row = i >> 5, k = i & 31;
      int g = gIdx[row];
      bf16 v = __float2bfloat16(0.f);
      if (g >= 0 && k < 14) v = (k < 6) ? in0[(size_t)g * 6 + k] : in1[(size_t)g * 8 + (k - 6)];
      Zt[row * SK + k] = v;
    }
  }
  __syncthreads();

  const bf16* W1t = W1p + (size_t)t * w1s;
  const bf16* W2t = W2p + (size_t)t * w2s;
  floatx4 acc[RT][2];
  #pragma unroll
  for (int rt = 0; rt < RT; rt++)
    #pragma unroll
    for (int c = 0; c < 2; c++) acc[rt][c] = (floatx4){0.f, 0.f, 0.f, 0.f};
  #pragma unroll
  for (int ks = 0; ks < KS1; ks++) {
    short8 bfr0 = *(const short8*)(W1t + (((size_t)(wave * 2 + 0) * KS1 + ks) * 64 + lane) * 8);
    short8 bfr1 = *(const short8*)(W1t + (((size_t)(wave * 2 + 1) * KS1 + ks) * 64 + lane) * 8);
    #pragma unroll
    for (int rt = 0; rt < RT; rt++) {
      short8 a = *(const short8*)(&Zt[(rt * 16 + colq) * SK + ks * 32 + quad * 8]);
      acc[rt][0] = __builtin_amdgcn_mfma_f32_16x16x32_bf16(a, bfr0, acc[rt][0], 0, 0, 0);
      acc[rt][1] = __builtin_amdgcn_mfma_f32_16x16x32_bf16(a, bfr1, acc[rt][1], 0, 0, 0);
    }
  }
  #pragma unroll
  for (int c = 0; c < 2; c++) {
    int col = wave * 32 + c * 16 + colq;
    float bv = b2f(b1v[t * b1s + col]);
    #pragma unroll
    for (int rt = 0; rt < RT; rt++)
      #pragma unroll
      for (int r = 0; r < 4; r++) {
        float v = acc[rt][c][r] + bv;
        Hid[(rt * 16 + quad * 4 + r) * HS + col] = __float2bfloat16(fmaxf(v, 0.f));
      }
  }
  __syncthreads();

  floatx4 acc2[RT][2];
  #pragma unroll
  for (int rt = 0; rt < RT; rt++)
    #pragma unroll
    for (int c = 0; c < 2; c++) acc2[rt][c] = (floatx4){0.f, 0.f, 0.f, 0.f};
  #pragma unroll
  for (int ks = 0; ks < 4; ks++) {
    short8 bfr0 = *(const short8*)(W2t + (((size_t)(wave * 2 + 0) * 4 + ks) * 64 + lane) * 8);
    short8 bfr1 = *(const short8*)(W2t + (((size_t)(wave * 2 + 1) * 4 + ks) * 64 + lane) * 8);
    #pragma unroll
    for (int rt = 0; rt < RT; rt++) {
      short8 a = *(const short8*)(&Hid[(rt * 16 + colq) * HS + ks * 32 + quad * 8]);
      acc2[rt][0] = __builtin_amdgcn_mfma_f32_16x16x32_bf16(a, bfr0, acc2[rt][0], 0, 0, 0);
      acc2[rt][1] = __builtin_amdgcn_mfma_f32_16x16x32_bf16(a, bfr1, acc2[rt][1], 0, 0, 0);
    }
  }
  if (DEC) {
    if (wave == 0 && colq < 4) {
      float bv = b2f(b2v[t * b2s + colq]);
      #pragma unroll
      for (int rt = 0; rt < RT; rt++)
        #pragma unroll
        for (int r = 0; r < 4; r++) {
          int g = gIdx[rt * 16 + quad * 4 + r];
          if (g >= 0) outp[(size_t)g * 4 + colq] = __float2bfloat16(acc2[rt][0][r] + bv);
        }
    }
  } else {
    #pragma unroll
    for (int c = 0; c < 2; c++) {
      int col = wave * 32 + c * 16 + colq;
      float bv = b2f(b2v[t * b2s + col]);
      #pragma unroll
      for (int rt = 0; rt < RT; rt++)
        #pragma unroll
        for (int r = 0; r < 4; r++) {
          int g = gIdx[rt * 16 + quad * 4 + r];
          if (g >= 0) outp[(size_t)g * HDIM + col] = __float2bfloat16(acc2[rt][c][r] + bv);
        }
    }
  }
}

// -------------------------------------------------- generic fused 2-layer MLP (ee/nu/fu)
template<int NPARTS, int KS1, int RES_PART, int BM, int HID_OFF, bool ATTR4>
__global__ void __launch_bounds__(256) mlp2_kernel(
    const bf16* __restrict__ p0, const int* __restrict__ idx0,
    const bf16* __restrict__ p1,
    const bf16* __restrict__ W1p, const bf16* __restrict__ b1v,
    const bf16* __restrict__ W2p, const bf16* __restrict__ b2v,
    bf16* __restrict__ outp, int M) {
  constexpr int RT = BM / 16;
  constexpr int SK = NPARTS * 128 + 8;
  __shared__ bf16 Zt[BM * SK];
  bf16* Hid = &Zt[HID_OFF];
  const int tid = threadIdx.x;
  const int lane = tid & 63, wave = tid >> 6, colq = lane & 15, quad = lane >> 4;
  const int row0 = blockIdx.x * BM;

  if (ATTR4) {
    for (int i = tid; i < BM * 4; i += 256) {
      int row = i >> 2, seg = i & 3;
      int gr = row0 + row;
      uint4 val = {0u, 0u, 0u, 0u};
      if (seg == 0 && gr < M) {
        int g = idx0 ? idx0[gr] : gr;
        uint2 v = *(const uint2*)(p0 + (size_t)g * 4);
        val.x = v.x; val.y = v.y;
      }
      *(uint4*)(&Zt[row * SK + seg * 8]) = val;
    }
  } else {
    constexpr int TPR = 256 / BM;
    constexpr int PT = NPARTS * 16 / TPR;
    int row = tid / TPR, sub = tid % TPR;
    int gr = row0 + row;
    bool ok = (gr < M);
    #pragma unroll
    for (int j = 0; j < PT; j++) {
      int c = j * TPR + sub;
      int part = c >> 4, seg = c & 15;
      uint4 val = {0u, 0u, 0u, 0u};
      if (ok) {
        const bf16* p = (part == 0) ? p0 : p1;
        val = *(const uint4*)(p + (size_t)gr * HDIM + seg * 8);
      }
      *(uint4*)(&Zt[row * SK + part * 128 + seg * 8]) = val;
    }
  }
  __syncthreads();

  floatx4 acc[RT][2];
  #pragma unroll
  for (int rt = 0; rt < RT; rt++)
    #pragma unroll
    for (int c = 0; c < 2; c++) acc[rt][c] = (floatx4){0.f, 0.f, 0.f, 0.f};
  #pragma unroll
  for (int ks = 0; ks < KS1; ks++) {
    short8 bfr0 = *(const short8*)(W1p + (((size_t)(wave * 2 + 0) * KS1 + ks) * 64 + lane) * 8);
    short8 bfr1 = *(const short8*)(W1p + (((size_t)(wave * 2 + 1) * KS1 + ks) * 64 + lane) * 8);
    #pragma unroll
    for (int rt = 0; rt < RT; rt++) {
      short8 a = *(const short8*)(&Zt[(rt * 16 + colq) * SK + ks * 32 + quad * 8]);
      acc[rt][0] = __builtin_amdgcn_mfma_f32_16x16x32_bf16(a, bfr0, acc[rt][0], 0, 0, 0);
      acc[rt][1] = __builtin_amdgcn_mfma_f32_16x16x32_bf16(a, bfr1, acc[rt][1], 0, 0, 0);
    }
  }
  __syncthreads();

  #pragma unroll
  for (int c = 0; c < 2; c++) {
    int col = wave * 32 + c * 16 + colq;
    float bv = b2f(b1v[col]);
    #pragma unroll
    for (int rt = 0; rt < RT; rt++)
      #pragma unroll
      for (int r = 0; r < 4; r++) {
        float v = acc[rt][c][r] + bv;
        Hid[(rt * 16 + quad * 4 + r) * SK + col] = __float2bfloat16(fmaxf(v, 0.f));
      }
  }
  __syncthreads();

  floatx4 acc2[RT][2];
  #pragma unroll
  for (int rt = 0; rt < RT; rt++)
    #pragma unroll
    for (int c = 0; c < 2; c++) acc2[rt][c] = (floatx4){0.f, 0.f, 0.f, 0.f};
  #pragma unroll
  for (int ks = 0; ks < 4; ks++) {
    short8 bfr0 = *(const short8*)(W2p + (((size_t)(wave * 2 + 0) * 4 + ks) * 64 + lane) * 8);
    short8 bfr1 = *(const short8*)(W2p + (((size_t)(wave * 2 + 1) * 4 + ks) * 64 + lane) * 8);
    #pragma unroll
    for (int rt = 0; rt < RT; rt++) {
      short8 a = *(const short8*)(&Hid[(rt * 16 + colq) * SK + ks * 32 + quad * 8]);
      acc2[rt][0] = __builtin_amdgcn_mfma_f32_16x16x32_bf16(a, bfr0, acc2[rt][0], 0, 0, 0);
      acc2[rt][1] = __builtin_amdgcn_mfma_f32_16x16x32_bf16(a, bfr1, acc2[rt][1], 0, 0, 0);
    }
  }
  #pragma unroll
  for (int c = 0; c < 2; c++) {
    int col = wave * 32 + c * 16 + colq;
    float bv = b2f(b2v[col]);
    #pragma unroll
    for (int rt = 0; rt < RT; rt++)
      #pragma unroll
      for (int r = 0; r < 4; r++) {
        int lrow = rt * 16 + quad * 4 + r;
        int grow = row0 + lrow;
        if (grow < M) {
          float v = acc2[rt][c][r] + bv;
          if constexpr (RES_PART >= 0)
            v += b2f(Zt[lrow * SK + RES_PART * 128 + col]);
          outp[(size_t)grow * HDIM + col] = __float2bfloat16(v);
        }
      }
  }
}

// ---------------------------------------------------------------- launcher
extern "C" void kernel_launch(void* const* d_in, const int* in_sizes, int n_in,
                              void* d_out, int out_size, void* d_ws, size_t ws_size,
                              hipStream_t stream) {
  const int* edge_index = (const int*)d_in[27];
  const int* node_types = (const int*)d_in[28];
  const int N = in_sizes[28];
  const int E = in_sizes[2] / 4;
  const int L = in_sizes[12] / HDIM;
  const int* srcI = edge_index;
  const int* dstI = edge_index + E;

  CanonDesc cd;
  int total = 0;
  for (int i = 0; i < NCANON; i++) { cd.src[i] = d_in[i]; cd.prefix[i] = total; total += in_sizes[i]; }
  cd.prefix[NCANON] = total;

  char* wsb = (char*)d_ws;
  size_t off = 0;
  auto alloc = [&](size_t bytes) -> void* {
    void* p = wsb + off;
    off += (bytes + 255) & ~(size_t)255;
    return p;
  };
  int*  flag      = (int*)alloc(256);
  bf16* arena     = (bf16*)alloc((size_t)total * 2);
  bf16* h_nodes   = (bf16*)alloc((size_t)N * HDIM * 2);
  bf16* h_edges   = (bf16*)alloc((size_t)E * HDIM * 2);
  bf16* m_node    = (bf16*)alloc((size_t)N * HDIM * 2);
  bf16* localb    = (bf16*)alloc((size_t)N * HDIM * 2);
  bf16* ysrcb     = (bf16*)alloc((size_t)N * HDIM * 2);
  bf16* ydstb     = (bf16*)alloc((size_t)N * HDIM * 2);
  bf16* canon_out = (bf16*)alloc((size_t)out_size * 2);
  int* counts     = (int*)alloc((size_t)N * 4);
  int* cursor     = (int*)alloc((size_t)N * 4);
  int* row_start  = (int*)alloc((size_t)(N + 1) * 4);
  int* bsum       = (int*)alloc(260 * 4);
  int* sortedE    = (int*)alloc((size_t)E * 4);
  int* srcS       = (int*)alloc((size_t)E * 4);
  int* dstS       = (int*)alloc((size_t)E * 4);
  int* tcnt       = (int*)alloc(16);
  int* tcur       = (int*)alloc(16);
  int* tsArr      = (int*)alloc(16);
  int* permT      = (int*)alloc((size_t)N * 4);
  bf16* eeW1p  = (bf16*)alloc(4096 * 2);
  bf16* eeW2p  = (bf16*)alloc(16384 * 2);
  bf16* encW1p = (bf16*)alloc(3 * 4096 * 2);
  bf16* encW2p = (bf16*)alloc(3 * 16384 * 2);
  bf16* decW1p = (bf16*)alloc(3 * 16384 * 2);
  bf16* decW2p = (bf16*)alloc(3 * 16384 * 2);
  bf16* euW1a  = (bf16*)alloc((size_t)L * 16384 * 2);
  bf16* euW1b  = (bf16*)alloc((size_t)L * 16384 * 2);
  bf16* euW1c  = (bf16*)alloc((size_t)L * 16384 * 2);
  bf16* euW2p  = (bf16*)alloc((size_t)L * 16384 * 2);
  bf16* nuW1p  = (bf16*)alloc((size_t)L * 32768 * 2);
  bf16* nuW2p  = (bf16*)alloc((size_t)L * 16384 * 2);
  bf16* fuW1p  = (bf16*)alloc((size_t)L * 16384 * 2);
  bf16* fuW2p  = (bf16*)alloc((size_t)L * 16384 * 2);

  const bf16* cX     = arena + cd.prefix[0];
  const bf16* cPE    = arena + cd.prefix[1];
  const bf16* cEA    = arena + cd.prefix[2];
  const bf16* cEncW1 = arena + cd.prefix[3];
  const bf16* cEncB1 = arena + cd.prefix[4];
  const bf16* cEncW2 = arena + cd.prefix[5];
  const bf16* cEncB2 = arena + cd.prefix[6];
  const bf16* cEeW1  = arena + cd.prefix[7];
  const bf16* cEeB1  = arena + cd.prefix[8];
  const bf16* cEeW2  = arena + cd.prefix[9];
  const bf16* cEeB2  = arena + cd.prefix[10];
  const bf16* cEuW1  = arena + cd.prefix[11];
  const bf16* cEuB1  = arena + cd.prefix[12];
  const bf16* cEuW2  = arena + cd.prefix[13];
  const bf16* cEuB2  = arena + cd.prefix[14];
  const bf16* cNuW1  = arena + cd.prefix[15];
  const bf16* cNuB1  = arena + cd.prefix[16];
  const bf16* cNuW2  = arena + cd.prefix[17];
  const bf16* cNuB2  = arena + cd.prefix[18];
  const bf16* cFuW1  = arena + cd.prefix[19];
  const bf16* cFuB1  = arena + cd.prefix[20];
  const bf16* cFuW2  = arena + cd.prefix[21];
  const bf16* cFuB2  = arena + cd.prefix[22];
  const bf16* cDecW1 = arena + cd.prefix[23];
  const bf16* cDecB1 = arena + cd.prefix[24];
  const bf16* cDecW2 = arena + cd.prefix[25];
  const bf16* cDecB2 = arena + cd.prefix[26];

  detect_kernel<<<1, 64, 0, stream>>>((const unsigned short*)d_in[0], flag);
  canon_kernel<<<(total + 255) / 256, 256, 0, stream>>>(cd, flag, arena, total);

  hipMemsetAsync(counts, 0, (size_t)N * 4, stream);
  hipMemsetAsync(cursor, 0, (size_t)N * 4, stream);
  hipMemsetAsync(tcnt, 0, 16, stream);
  hipMemsetAsync(tcur, 0, 16, stream);

  PackJobs PJ;
  int nj = 0;
  PJ.j[nj++] = {cEeW1, eeW1p, 4, 1, 128};
  PJ.j[nj++] = {cEeW2, eeW2p, 128, 4, 128};
  for (int l = 0; l < L; l++) {
    const bf16* w1 = cEuW1 + (size_t)l * 384 * HDIM;
    PJ.j[nj++] = {w1,                 euW1a + (size_t)l * 16384, 128, 4, 128};
    PJ.j[nj++] = {w1 + 128 * HDIM,    euW1b + (size_t)l * 16384, 128, 4, 128};
    PJ.j[nj++] = {w1 + 256 * HDIM,    euW1c + (size_t)l * 16384, 128, 4, 128};
    PJ.j[nj++] = {cEuW2 + (size_t)l * HDIM * HDIM, euW2p + (size_t)l * 16384, 128, 4, 128};
    PJ.j[nj++] = {cNuW1 + (size_t)l * 256 * HDIM,  nuW1p + (size_t)l * 32768, 256, 8, 128};
    PJ.j[nj++] = {cNuW2 + (size_t)l * HDIM * HDIM, nuW2p + (size_t)l * 16384, 128, 4, 128};
    PJ.j[nj++] = {cFuW1 + (size_t)l * HDIM * HDIM, fuW1p + (size_t)l * 16384, 128, 4, 128};
    PJ.j[nj++] = {cFuW2 + (size_t)l * HDIM * HDIM, fuW2p + (size_t)l * 16384, 128, 4, 128};
  }
  for (int t = 0; t < 3; t++) {
    PJ.j[nj++] = {cEncW1 + (size_t)t * 14 * HDIM,   encW1p + (size_t)t * 4096, 14, 1, 128};
    PJ.j[nj++] = {cEncW2 + (size_t)t * HDIM * HDIM, encW2p + (size_t)t * 16384, 128, 4, 128};
    PJ.j[nj++] = {cDecW1 + (size_t)t * HDIM * HDIM, decW1p + (size_t)t * 16384, 128, 4, 128};
    PJ.j[nj++] = {cDecW2 + (size_t)t * HDIM * 4,    decW2p + (size_t)t * 16384, 128, 4, 4};
  }
  pack_all_kernel<<<dim3(16, nj), 256, 0, stream>>>(PJ);

  // CSR (dst-sorted edges)
  int nb = (N + 255) / 256;
  hist_kernel<<<(E + 255) / 256, 256, 0, stream>>>(dstI, counts, E);
  scan1_kernel<<<nb, 256, 0, stream>>>(counts, bsum, N);
  scan2_kernel<<<1, 64, 0, stream>>>(bsum, nb);
  scan3_kernel<<<nb, 256, 0, stream>>>(counts, bsum, row_start, N, nb);
  scatter_kernel<<<(E + 255) / 256, 256, 0, stream>>>(srcI, dstI, row_start, cursor,
                                                      sortedE, srcS, dstS, E);
  // type-sorted node permutation
  thist_kernel<<<(N + 255) / 256, 256, 0, stream>>>(node_types, tcnt, N);
  toff_kernel<<<1, 1, 0, stream>>>(tcnt, tsArr);
  tscatter_kernel<<<(N + 255) / 256, 256, 0, stream>>>(node_types, tsArr, tcur, permT, N);

  int ngrid64 = (N + 63) / 64;
  // typed encoder
  typed_kernel<1, false><<<dim3(ngrid64, 3), 256, 0, stream>>>(
      cX, cPE, permT, tsArr, encW1p, 4096, cEncB1, HDIM,
      encW2p, 16384, cEncB2, HDIM, h_nodes);

  int egrid32  = (E + 31) / 32;
  int egrid128 = (E + 127) / 128;
  int ngrid128 = (N + 127) / 128;

  // edge encoder -> h_edges (dst-sorted order via sortedE gather)
  mlp2_kernel<1, 1, -1, 128, 0, true><<<egrid128, 256, 0, stream>>>(
      cEA, sortedE, nullptr, eeW1p, cEeB1, eeW2p, cEeB2, h_edges, E);

  for (int l = 0; l < L; l++) {
    // per-node Y = h_nodes @ W1a / W1b
    ygemm_kernel<<<dim3(ngrid64, 2), 256, 0, stream>>>(
        h_nodes, euW1a + (size_t)l * 16384, euW1b + (size_t)l * 16384, ysrcb, ydstb, N);
    // edge update with ysum trick
    eu_kernel<32><<<egrid32, 256, 0, stream>>>(
        h_edges, ysrcb, ydstb, srcS, dstS,
        euW1c + (size_t)l * 16384, cEuB1 + l * HDIM,
        euW2p + (size_t)l * 16384, cEuB2 + l * HDIM, h_edges, E);
    aggregate_kernel<<<(N + 3) / 4, 256, 0, stream>>>(h_edges, row_start, m_node, N);
    mlp2_kernel<2, 8, 0, 64, 128, false><<<ngrid64, 256, 0, stream>>>(
        h_nodes, nullptr, m_node,
        nuW1p + (size_t)l * 32768, cNuB1 + l * HDIM,
        nuW2p + (size_t)l * 16384, cNuB2 + l * HDIM, localb, N);
    mlp2_kernel<1, 4, -1, 128, 0, false><<<ngrid128, 256, 0, stream>>>(
        localb, nullptr, nullptr,
        fuW1p + (size_t)l * 16384, cFuB1 + l * HDIM,
        fuW2p + (size_t)l * 16384, cFuB2 + l * HDIM, h_nodes, N);
  }

  // typed decoder
  typed_kernel<4, true><<<dim3(ngrid64, 3), 256, 0, stream>>>(
      h_nodes, nullptr, permT, tsArr, decW1p, 16384, cDecB1, HDIM,
      decW2p, 16384, cDecB2, 4, canon_out);
  emit_kernel<<<(out_size + 255) / 256, 256, 0, stream>>>(canon_out, flag, d_out, out_size);
  (void)n_in; (void)ws_size;
}

// Round 6
// 537.506 us; speedup vs baseline: 1.4825x; 1.4825x over previous
//
#include <hip/hip_runtime.h>
#include <hip/hip_bf16.h>

typedef __hip_bfloat16 bf16;
typedef __attribute__((ext_vector_type(8))) short short8;   // 8 bf16 frag
typedef __attribute__((ext_vector_type(4))) float floatx4;  // MFMA C/D frag

#define HDIM 128
#define NCANON 27

__device__ __forceinline__ float b2f(bf16 v) { return __bfloat162float(v); }
__device__ __forceinline__ float s2f(short s) {
  return __uint_as_float(((unsigned int)(unsigned short)s) << 16);
}

// ------------------------------------------------- dtype detect (bf16 vs f32)
__global__ void detect_kernel(const unsigned short* __restrict__ xraw, int* __restrict__ flag) {
  int j = threadIdx.x;                      // 64 threads
  unsigned short u = xraw[2 * j];
  int e = (u >> 7) & 0xFF;
  int ok = (u == 0) || (e >= 100 && e <= 140);
  unsigned long long m = __ballot(ok);
  if (j == 0) flag[0] = (__popcll(m) >= 48) ? 1 : 0;   // 1 = bf16 storage
}

struct CanonDesc {
  const void* src[NCANON];
  int prefix[NCANON + 1];
};

__global__ void canon_kernel(CanonDesc d, const int* __restrict__ flag,
                             bf16* __restrict__ out, int total) {
  int t = blockIdx.x * 256 + threadIdx.x;
  if (t >= total) return;
  int ti = 0;
  while (d.prefix[ti + 1] <= t) ti++;
  int off = t - d.prefix[ti];
  if (flag[0]) out[t] = ((const bf16*)d.src[ti])[off];
  else         out[t] = __float2bfloat16(((const float*)d.src[ti])[off]);
}

__global__ void emit_kernel(const bf16* __restrict__ canon_out, const int* __restrict__ flag,
                            void* __restrict__ d_out, int n) {
  int t = blockIdx.x * 256 + threadIdx.x;
  if (t >= n) return;
  if (flag[0]) ((bf16*)d_out)[t] = canon_out[t];
  else         ((float*)d_out)[t] = __bfloat162float(canon_out[t]);
}

// ---------------------------------------------------------------- CSR build
__global__ void hist_kernel(const int* __restrict__ dst, int* __restrict__ cnt, int E) {
  int e = blockIdx.x * 256 + threadIdx.x;
  if (e < E) atomicAdd(&cnt[dst[e]], 1);
}

__global__ void scan1_kernel(const int* __restrict__ cnt, int* __restrict__ bsum, int n) {
  int tid = threadIdx.x, lane = tid & 63, wave = tid >> 6;
  int i = blockIdx.x * 256 + tid;
  int v = (i < n) ? cnt[i] : 0;
  #pragma unroll
  for (int d = 32; d; d >>= 1) v += __shfl_down(v, d);
  __shared__ int ws[4];
  if (lane == 0) ws[wave] = v;
  __syncthreads();
  if (tid == 0) bsum[blockIdx.x] = ws[0] + ws[1] + ws[2] + ws[3];
}

__global__ void scan2_kernel(int* __restrict__ bsum, int nb) {   // nb <= 128; 64 threads
  int lane = threadIdx.x;
  int a0 = (lane < nb) ? bsum[lane] : 0;
  int b0 = (64 + lane < nb) ? bsum[64 + lane] : 0;
  int a = a0, b = b0;
  #pragma unroll
  for (int d = 1; d < 64; d <<= 1) { int t = __shfl_up(a, d); if (lane >= d) a += t; }
  int totA = __shfl(a, 63);
  #pragma unroll
  for (int d = 1; d < 64; d <<= 1) { int t = __shfl_up(b, d); if (lane >= d) b += t; }
  int totB = __shfl(b, 63);
  if (lane < nb) bsum[lane] = a - a0;
  if (64 + lane < nb) bsum[64 + lane] = b - b0 + totA;
  if (lane == 0) bsum[nb] = totA + totB;
}

__global__ void scan3_kernel(const int* __restrict__ cnt, const int* __restrict__ bsum,
                             int* __restrict__ row_start, int n, int nb) {
  __shared__ int sh[256];
  int tid = threadIdx.x;
  int i = blockIdx.x * 256 + tid;
  int v = (i < n) ? cnt[i] : 0;
  sh[tid] = v;
  __syncthreads();
  #pragma unroll
  for (int off = 1; off < 256; off <<= 1) {
    int t = (tid >= off) ? sh[tid - off] : 0;
    __syncthreads();
    sh[tid] += t;
    __syncthreads();
  }
  if (i < n) row_start[i] = bsum[blockIdx.x] + sh[tid] - v;
  if (blockIdx.x == 0 && tid == 0) row_start[n] = bsum[nb];
}

__global__ void scatter_kernel(const int* __restrict__ src, const int* __restrict__ dst,
                               const int* __restrict__ row_start, int* __restrict__ cursor,
                               int* __restrict__ sortedE, int* __restrict__ srcS,
                               int* __restrict__ dstS, int E) {
  int e = blockIdx.x * 256 + threadIdx.x;
  if (e < E) {
    int d = dst[e];
    int pos = row_start[d] + atomicAdd(&cursor[d], 1);
    sortedE[pos] = e;
    srcS[pos] = src[e];
    dstS[pos] = d;
  }
}

// --------------------------------- type permutation: atomic-free counting sort
__global__ void tcount_kernel(const int* __restrict__ types, int* __restrict__ bcnt, int n) {
  int i = blockIdx.x * 256 + threadIdx.x;
  int lane = threadIdx.x & 63, wave = threadIdx.x >> 6;
  int t = (i < n) ? types[i] : -1;
  __shared__ int wc[4][3];
  unsigned long long m0 = __ballot(t == 0);
  unsigned long long m1 = __ballot(t == 1);
  unsigned long long m2 = __ballot(t == 2);
  if (lane == 0) {
    wc[wave][0] = __popcll(m0); wc[wave][1] = __popcll(m1); wc[wave][2] = __popcll(m2);
  }
  __syncthreads();
  if (threadIdx.x < 3)
    bcnt[blockIdx.x * 3 + threadIdx.x] =
        wc[0][threadIdx.x] + wc[1][threadIdx.x] + wc[2][threadIdx.x] + wc[3][threadIdx.x];
}

// one wave: per-type exclusive scan over <=128 block counts + type bases; emits ts[0..3]
__global__ void tscan_kernel(const int* __restrict__ bcnt, int* __restrict__ boff,
                             int* __restrict__ ts, int nb, int n) {
  int lane = threadIdx.x;   // 64
  __shared__ int tots[3];
  for (int t = 0; t < 3; t++) {
    int a0 = (lane < nb) ? bcnt[lane * 3 + t] : 0;
    int b0 = (64 + lane < nb) ? bcnt[(64 + lane) * 3 + t] : 0;
    int a = a0, b = b0;
    #pragma unroll
    for (int d = 1; d < 64; d <<= 1) { int x = __shfl_up(a, d); if (lane >= d) a += x; }
    int totA = __shfl(a, 63);
    #pragma unroll
    for (int d = 1; d < 64; d <<= 1) { int x = __shfl_up(b, d); if (lane >= d) b += x; }
    int totB = __shfl(b, 63);
    if (lane < nb) boff[lane * 3 + t] = a - a0;
    if (64 + lane < nb) boff[(64 + lane) * 3 + t] = b - b0 + totA;
    if (lane == 0) tots[t] = totA + totB;
  }
  __syncthreads();
  int tot0 = tots[0], tot1 = tots[1];
  if (lane == 0) { ts[0] = 0; ts[1] = tot0; ts[2] = tot0 + tot1; ts[3] = n; }
  for (int idx = lane; idx < nb; idx += 64) {
    boff[idx * 3 + 1] += tot0;
    boff[idx * 3 + 2] += tot0 + tot1;
  }
}

__global__ void tscatter2_kernel(const int* __restrict__ types, const int* __restrict__ boff,
                                 int* __restrict__ perm, int n) {
  int i = blockIdx.x * 256 + threadIdx.x;
  int lane = threadIdx.x & 63, wave = threadIdx.x >> 6;
  int t = (i < n) ? types[i] : -1;
  __shared__ int wc[4][3];
  unsigned long long m0 = __ballot(t == 0);
  unsigned long long m1 = __ballot(t == 1);
  unsigned long long m2 = __ballot(t == 2);
  if (lane == 0) {
    wc[wave][0] = __popcll(m0); wc[wave][1] = __popcll(m1); wc[wave][2] = __popcll(m2);
  }
  __syncthreads();
  if (i >= n) return;
  unsigned long long mt = (t == 0) ? m0 : ((t == 1) ? m1 : m2);
  unsigned long long below = (lane == 0) ? 0ull : ((1ull << lane) - 1ull);
  int laneRank = __popcll(mt & below);
  int waveOff = 0;
  for (int w = 0; w < wave; w++) waveOff += wc[w][t];
  perm[boff[blockIdx.x * 3 + t] + waveOff + laneRank] = i;
}

// ------------------------------------------------------------- aggregation
__global__ void aggregate_kernel(const bf16* __restrict__ h_edges, const int* __restrict__ row_start,
                                 bf16* __restrict__ m_node, int n) {
  int node = blockIdx.x * 4 + (threadIdx.x >> 6);
  if (node >= n) return;
  int lane = threadIdx.x & 63;
  int chunk = lane & 15;
  int sub = lane >> 4;
  int s = row_start[node], e = row_start[node + 1];
  float acc[8];
  #pragma unroll
  for (int j = 0; j < 8; j++) acc[j] = 0.f;
  for (int p = s + sub; p < e; p += 4) {
    short8 v = *(const short8*)(h_edges + (size_t)p * HDIM + chunk * 8);
    #pragma unroll
    for (int j = 0; j < 8; j++) acc[j] += s2f(v[j]);
  }
  #pragma unroll
  for (int j = 0; j < 8; j++) {
    acc[j] += __shfl_xor(acc[j], 16);
    acc[j] += __shfl_xor(acc[j], 32);
  }
  if (sub == 0) {
    short8 o;
    #pragma unroll
    for (int j = 0; j < 8; j++) o[j] = (short)__bfloat16_as_ushort(__float2bfloat16(acc[j]));
    *(short8*)(m_node + (size_t)node * HDIM + chunk * 8) = o;
  }
}

// -------------------------------------------------- fused weight pre-pack (B-frag order)
struct PackJob { const bf16* src; bf16* dst; int Ksrc; int KS; int srcCols; };
struct PackJobs { PackJob j[40]; };

__global__ void pack_all_kernel(PackJobs J) {
  PackJob job = J.j[blockIdx.y];
  int idx = blockIdx.x * 256 + threadIdx.x;
  int total = 8 * job.KS * 64;
  if (idx >= total) return;
  int lane = idx & 63;
  int ks = (idx >> 6) % job.KS;
  int ct = idx / (64 * job.KS);
  bf16* o = job.dst + (size_t)idx * 8;
  int ncol = ct * 16 + (lane & 15);
  int kb = ks * 32 + ((lane >> 4) & 3) * 8;
  #pragma unroll
  for (int jj = 0; jj < 8; jj++) {
    int k = kb + jj;
    o[jj] = (k < job.Ksrc && ncol < job.srcCols)
              ? job.src[(size_t)k * job.srcCols + ncol] : __float2bfloat16(0.f);
  }
}

// -------------------------------------------------- single-GEMM node kernel (Y = X @ W)
__global__ void __launch_bounds__(256) ygemm_kernel(
    const bf16* __restrict__ X,
    const bf16* __restrict__ WpA, const bf16* __restrict__ WpB,
    bf16* __restrict__ outA, bf16* __restrict__ outB, int M) {
  const bf16* Wp = blockIdx.y ? WpB : WpA;
  bf16* outp = blockIdx.y ? outB : outA;
  constexpr int BM = 64, RT = 4, SK = 136;
  __shared__ bf16 Zt[BM * SK];
  const int tid = threadIdx.x;
  const int lane = tid & 63, wave = tid >> 6, colq = lane & 15, quad = lane >> 4;
  const int row0 = blockIdx.x * BM;
  {
    int row = tid >> 2, sub = tid & 3;
    int gr = row0 + row;
    bool ok = gr < M;
    #pragma unroll
    for (int j = 0; j < 4; j++) {
      int seg = j * 4 + sub;
      uint4 v = {0u, 0u, 0u, 0u};
      if (ok) v = *(const uint4*)(X + (size_t)gr * HDIM + seg * 8);
      *(uint4*)(&Zt[row * SK + seg * 8]) = v;
    }
  }
  __syncthreads();
  floatx4 acc[RT][2];
  #pragma unroll
  for (int rt = 0; rt < RT; rt++)
    #pragma unroll
    for (int c = 0; c < 2; c++) acc[rt][c] = (floatx4){0.f, 0.f, 0.f, 0.f};
  #pragma unroll
  for (int ks = 0; ks < 4; ks++) {
    short8 bfr0 = *(const short8*)(Wp + (((size_t)(wave * 2 + 0) * 4 + ks) * 64 + lane) * 8);
    short8 bfr1 = *(const short8*)(Wp + (((size_t)(wave * 2 + 1) * 4 + ks) * 64 + lane) * 8);
    #pragma unroll
    for (int rt = 0; rt < RT; rt++) {
      short8 a = *(const short8*)(&Zt[(rt * 16 + colq) * SK + ks * 32 + quad * 8]);
      acc[rt][0] = __builtin_amdgcn_mfma_f32_16x16x32_bf16(a, bfr0, acc[rt][0], 0, 0, 0);
      acc[rt][1] = __builtin_amdgcn_mfma_f32_16x16x32_bf16(a, bfr1, acc[rt][1], 0, 0, 0);
    }
  }
  #pragma unroll
  for (int c = 0; c < 2; c++) {
    int col = wave * 32 + c * 16 + colq;
    #pragma unroll
    for (int rt = 0; rt < RT; rt++)
      #pragma unroll
      for (int r = 0; r < 4; r++) {
        int grow = row0 + rt * 16 + quad * 4 + r;
        if (grow < M) outp[(size_t)grow * HDIM + col] = __float2bfloat16(acc[rt][c][r]);
      }
  }
}

// -------------------------------------------------- edge-update kernel (ysum trick)
// out = h_e_old + (ReLU(h_e @ W1c + ysum + b1) @ W2 + b2)
// Zt part0 = ysum (becomes Hid in-place, per-lane element ownership), part1 = h_e.
template<int BM>
__global__ void __launch_bounds__(256) eu_kernel(
    const bf16* __restrict__ he, const bf16* __restrict__ ysrc, const bf16* __restrict__ ydst,
    const int* __restrict__ srcS, const int* __restrict__ dstS,
    const bf16* __restrict__ W1p, const bf16* __restrict__ b1v,
    const bf16* __restrict__ W2p, const bf16* __restrict__ b2v,
    bf16* __restrict__ outp, int M) {
  constexpr int RT = BM / 16;
  constexpr int SK = 264;
  __shared__ bf16 Zt[BM * SK];
  const int tid = threadIdx.x;
  const int lane = tid & 63, wave = tid >> 6, colq = lane & 15, quad = lane >> 4;
  const int row0 = blockIdx.x * BM;
  constexpr int TPR = 256 / BM;
  {
    int row = tid / TPR, sub = tid % TPR;
    int gr = row0 + row;
    bool ok = gr < M;
    int g0 = ok ? srcS[gr] : 0;
    int g1 = ok ? dstS[gr] : 0;
    #pragma unroll
    for (int j = 0; j < 32 / TPR; j++) {
      int c = j * TPR + sub;
      int part = c >> 4, seg = c & 15;
      if (part == 0) {
        short8 o = {0, 0, 0, 0, 0, 0, 0, 0};
        if (ok) {
          short8 a = *(const short8*)(ysrc + (size_t)g0 * HDIM + seg * 8);
          short8 b = *(const short8*)(ydst + (size_t)g1 * HDIM + seg * 8);
          #pragma unroll
          for (int k = 0; k < 8; k++)
            o[k] = (short)__bfloat16_as_ushort(__float2bfloat16(s2f(a[k]) + s2f(b[k])));
        }
        *(short8*)(&Zt[row * SK + seg * 8]) = o;
      } else {
        uint4 v = {0u, 0u, 0u, 0u};
        if (ok) v = *(const uint4*)(he + (size_t)gr * HDIM + seg * 8);
        *(uint4*)(&Zt[row * SK + 128 + seg * 8]) = v;
      }
    }
  }
  __syncthreads();

  floatx4 acc[RT][2];
  #pragma unroll
  for (int rt = 0; rt < RT; rt++)
    #pragma unroll
    for (int c = 0; c < 2; c++) acc[rt][c] = (floatx4){0.f, 0.f, 0.f, 0.f};
  #pragma unroll
  for (int ks = 0; ks < 4; ks++) {
    short8 bfr0 = *(const short8*)(W1p + (((size_t)(wave * 2 + 0) * 4 + ks) * 64 + lane) * 8);
    short8 bfr1 = *(const short8*)(W1p + (((size_t)(wave * 2 + 1) * 4 + ks) * 64 + lane) * 8);
    #pragma unroll
    for (int rt = 0; rt < RT; rt++) {
      short8 a = *(const short8*)(&Zt[(rt * 16 + colq) * SK + 128 + ks * 32 + quad * 8]);
      acc[rt][0] = __builtin_amdgcn_mfma_f32_16x16x32_bf16(a, bfr0, acc[rt][0], 0, 0, 0);
      acc[rt][1] = __builtin_amdgcn_mfma_f32_16x16x32_bf16(a, bfr1, acc[rt][1], 0, 0, 0);
    }
  }
  // epilogue: read ysum, write Hid in-place (same addr, same owning lane; part1 untouched)
  #pragma unroll
  for (int c = 0; c < 2; c++) {
    int col = wave * 32 + c * 16 + colq;
    float bv = b2f(b1v[col]);
    #pragma unroll
    for (int rt = 0; rt < RT; rt++)
      #pragma unroll
      for (int r = 0; r < 4; r++) {
        int lrow = rt * 16 + quad * 4 + r;
        float v = acc[rt][c][r] + bv + b2f(Zt[lrow * SK + col]);
        Zt[lrow * SK + col] = __float2bfloat16(fmaxf(v, 0.f));
      }
  }
  __syncthreads();

  floatx4 acc2[RT][2];
  #pragma unroll
  for (int rt = 0; rt < RT; rt++)
    #pragma unroll
    for (int c = 0; c < 2; c++) acc2[rt][c] = (floatx4){0.f, 0.f, 0.f, 0.f};
  #pragma unroll
  for (int ks = 0; ks < 4; ks++) {
    short8 bfr0 = *(const short8*)(W2p + (((size_t)(wave * 2 + 0) * 4 + ks) * 64 + lane) * 8);
    short8 bfr1 = *(const short8*)(W2p + (((size_t)(wave * 2 + 1) * 4 + ks) * 64 + lane) * 8);
    #pragma unroll
    for (int rt = 0; rt < RT; rt++) {
      short8 a = *(const short8*)(&Zt[(rt * 16 + colq) * SK + ks * 32 + quad * 8]);
      acc2[rt][0] = __builtin_amdgcn_mfma_f32_16x16x32_bf16(a, bfr0, acc2[rt][0], 0, 0, 0);
      acc2[rt][1] = __builtin_amdgcn_mfma_f32_16x16x32_bf16(a, bfr1, acc2[rt][1], 0, 0, 0);
    }
  }
  #pragma unroll
  for (int c = 0; c < 2; c++) {
    int col = wave * 32 + c * 16 + colq;
    float bv = b2f(b2v[col]);
    #pragma unroll
    for (int rt = 0; rt < RT; rt++)
      #pragma unroll
      for (int r = 0; r < 4; r++) {
        int lrow = rt * 16 + quad * 4 + r;
        int grow = row0 + lrow;
        if (grow < M) {
          float v = acc2[rt][c][r] + bv + b2f(Zt[lrow * SK + 128 + col]);
          outp[(size_t)grow * HDIM + col] = __float2bfloat16(v);
        }
      }
  }
}

// -------------------------------------------------- typed enc/dec (type-sorted MFMA)
template<int KS1, bool DEC>
__global__ void __launch_bounds__(256) typed_kernel(
    const bf16* __restrict__ in0, const bf16* __restrict__ in1,
    const int* __restrict__ perm, const int* __restrict__ ts,
    const bf16* __restrict__ W1p, int w1s, const bf16* __restrict__ b1v, int b1s,
    const bf16* __restrict__ W2p, int w2s, const bf16* __restrict__ b2v, int b2s,
    bf16* __restrict__ outp) {
  constexpr int BM = 64, RT = 4;
  constexpr int SK = KS1 * 32 + 8;
  constexpr int HS = 136;
  int t = blockIdx.y;
  int rs = ts[t], re = ts[t + 1];
  int row0 = rs + blockIdx.x * BM;
  if (row0 >= re) return;
  __shared__ bf16 Zt[BM * SK];
  __shared__ bf16 Hid[BM * HS];
  __shared__ int gIdx[BM];
  const int tid = threadIdx.x;
  const int lane = tid & 63, wave = tid >> 6, colq = lane & 15, quad = lane >> 4;
  for (int i = tid; i < BM; i += 256) gIdx[i] = (row0 + i < re) ? perm[row0 + i] : -1;
  __syncthreads();
  if (DEC) {
    int row = tid >> 2, sub = tid & 3;
    int g = gIdx[row];
    #pragma unroll
    for (int j = 0; j < 4; j++) {
      int seg = j * 4 + sub;
      uint4 v = {0u, 0u, 0u, 0u};
      if (g >= 0) v = *(const uint4*)(in0 + (size_t)g * HDIM + seg * 8);
      *(uint4*)(&Zt[row * SK + seg * 8]) = v;
    }
  } else {
    for (int i = tid; i < BM * 32; i += 256) {
      int row = i >> 5, k = i & 31;
      int g = gIdx[row];
      bf16 v = __float2bfloat16(0.f);
      if (g >= 0 && k < 14) v = (k < 6) ? in0[(size_t)g * 6 + k] : in1[(size_t)g * 8 + (k - 6)];
      Zt[row * SK + k] = v;
    }
  }
  __syncthreads();

  const bf16* W1t = W1p + (size_t)t * w1s;
  const bf16* W2t = W2p + (size_t)t * w2s;
  floatx4 acc[RT][2];
  #pragma unroll
  for (int rt = 0; rt < RT; rt++)
    #pragma unroll
    for (int c = 0; c < 2; c++) acc[rt][c] = (floatx4){0.f, 0.f, 0.f, 0.f};
  #pragma unroll
  for (int ks = 0; ks < KS1; ks++) {
    short8 bfr0 = *(const short8*)(W1t + (((size_t)(wave * 2 + 0) * KS1 + ks) * 64 + lane) * 8);
    short8 bfr1 = *(const short8*)(W1t + (((size_t)(wave * 2 + 1) * KS1 + ks) * 64 + lane) * 8);
    #pragma unroll
    for (int rt = 0; rt < RT; rt++) {
      short8 a = *(const short8*)(&Zt[(rt * 16 + colq) * SK + ks * 32 + quad * 8]);
      acc[rt][0] = __builtin_amdgcn_mfma_f32_16x16x32_bf16(a, bfr0, acc[rt][0], 0, 0, 0);
      acc[rt][1] = __builtin_amdgcn_mfma_f32_16x16x32_bf16(a, bfr1, acc[rt][1], 0, 0, 0);
    }
  }
  #pragma unroll
  for (int c = 0; c < 2; c++) {
    int col = wave * 32 + c * 16 + colq;
    float bv = b2f(b1v[t * b1s + col]);
    #pragma unroll
    for (int rt = 0; rt < RT; rt++)
      #pragma unroll
      for (int r = 0; r < 4; r++) {
        float v = acc[rt][c][r] + bv;
        Hid[(rt * 16 + quad * 4 + r) * HS + col] = __float2bfloat16(fmaxf(v, 0.f));
      }
  }
  __syncthreads();

  floatx4 acc2[RT][2];
  #pragma unroll
  for (int rt = 0; rt < RT; rt++)
    #pragma unroll
    for (int c = 0; c < 2; c++) acc2[rt][c] = (floatx4){0.f, 0.f, 0.f, 0.f};
  #pragma unroll
  for (int ks = 0; ks < 4; ks++) {
    short8 bfr0 = *(const short8*)(W2t + (((size_t)(wave * 2 + 0) * 4 + ks) * 64 + lane) * 8);
    short8 bfr1 = *(const short8*)(W2t + (((size_t)(wave * 2 + 1) * 4 + ks) * 64 + lane) * 8);
    #pragma unroll
    for (int rt = 0; rt < RT; rt++) {
      short8 a = *(const short8*)(&Hid[(rt * 16 + colq) * HS + ks * 32 + quad * 8]);
      acc2[rt][0] = __builtin_amdgcn_mfma_f32_16x16x32_bf16(a, bfr0, acc2[rt][0], 0, 0, 0);
      acc2[rt][1] = __builtin_amdgcn_mfma_f32_16x16x32_bf16(a, bfr1, acc2[rt][1], 0, 0, 0);
    }
  }
  if (DEC) {
    if (wave == 0 && colq < 4) {
      float bv = b2f(b2v[t * b2s + colq]);
      #pragma unroll
      for (int rt = 0; rt < RT; rt++)
        #pragma unroll
        for (int r = 0; r < 4; r++) {
          int g = gIdx[rt * 16 + quad * 4 + r];
          if (g >= 0) outp[(size_t)g * 4 + colq] = __float2bfloat16(acc2[rt][0][r] + bv);
        }
    }
  } else {
    #pragma unroll
    for (int c = 0; c < 2; c++) {
      int col = wave * 32 + c * 16 + colq;
      float bv = b2f(b2v[t * b2s + col]);
      #pragma unroll
      for (int rt = 0; rt < RT; rt++)
        #pragma unroll
        for (int r = 0; r < 4; r++) {
          int g = gIdx[rt * 16 + quad * 4 + r];
          if (g >= 0) outp[(size_t)g * HDIM + col] = __float2bfloat16(acc2[rt][c][r] + bv);
        }
    }
  }
}

// -------------------------------------------------- generic fused 2-layer MLP (ee/nu/fu)
template<int NPARTS, int KS1, int RES_PART, int BM, int HID_OFF, bool ATTR4>
__global__ void __launch_bounds__(256) mlp2_kernel(
    const bf16* __restrict__ p0, const int* __restrict__ idx0,
    const bf16* __restrict__ p1,
    const bf16* __restrict__ W1p, const bf16* __restrict__ b1v,
    const bf16* __restrict__ W2p, const bf16* __restrict__ b2v,
    bf16* __restrict__ outp, int M) {
  constexpr int RT = BM / 16;
  constexpr int SK = NPARTS * 128 + 8;
  __shared__ bf16 Zt[BM * SK];
  bf16* Hid = &Zt[HID_OFF];
  const int tid = threadIdx.x;
  const int lane = tid & 63, wave = tid >> 6, colq = lane & 15, quad = lane >> 4;
  const int row0 = blockIdx.x * BM;

  if (ATTR4) {
    for (int i = tid; i < BM * 4; i += 256) {
      int row = i >> 2, seg = i & 3;
      int gr = row0 + row;
      uint4 val = {0u, 0u, 0u, 0u};
      if (seg == 0 && gr < M) {
        int g = idx0 ? idx0[gr] : gr;
        uint2 v = *(const uint2*)(p0 + (size_t)g * 4);
        val.x = v.x; val.y = v.y;
      }
      *(uint4*)(&Zt[row * SK + seg * 8]) = val;
    }
  } else {
    constexpr int TPR = 256 / BM;
    constexpr int PT = NPARTS * 16 / TPR;
    int row = tid / TPR, sub = tid % TPR;
    int gr = row0 + row;
    bool ok = (gr < M);
    #pragma unroll
    for (int j = 0; j < PT; j++) {
      int c = j * TPR + sub;
      int part = c >> 4, seg = c & 15;
      uint4 val = {0u, 0u, 0u, 0u};
      if (ok) {
        const bf16* p = (part == 0) ? p0 : p1;
        val = *(const uint4*)(p + (size_t)gr * HDIM + seg * 8);
      }
      *(uint4*)(&Zt[row * SK + part * 128 + seg * 8]) = val;
    }
  }
  __syncthreads();

  floatx4 acc[RT][2];
  #pragma unroll
  for (int rt = 0; rt < RT; rt++)
    #pragma unroll
    for (int c = 0; c < 2; c++) acc[rt][c] = (floatx4){0.f, 0.f, 0.f, 0.f};
  #pragma unroll
  for (int ks = 0; ks < KS1; ks++) {
    short8 bfr0 = *(const short8*)(W1p + (((size_t)(wave * 2 + 0) * KS1 + ks) * 64 + lane) * 8);
    short8 bfr1 = *(const short8*)(W1p + (((size_t)(wave * 2 + 1) * KS1 + ks) * 64 + lane) * 8);
    #pragma unroll
    for (int rt = 0; rt < RT; rt++) {
      short8 a = *(const short8*)(&Zt[(rt * 16 + colq) * SK + ks * 32 + quad * 8]);
      acc[rt][0] = __builtin_amdgcn_mfma_f32_16x16x32_bf16(a, bfr0, acc[rt][0], 0, 0, 0);
      acc[rt][1] = __builtin_amdgcn_mfma_f32_16x16x32_bf16(a, bfr1, acc[rt][1], 0, 0, 0);
    }
  }
  __syncthreads();

  #pragma unroll
  for (int c = 0; c < 2; c++) {
    int col = wave * 32 + c * 16 + colq;
    float bv = b2f(b1v[col]);
    #pragma unroll
    for (int rt = 0; rt < RT; rt++)
      #pragma unroll
      for (int r = 0; r < 4; r++) {
        float v = acc[rt][c][r] + bv;
        Hid[(rt * 16 + quad * 4 + r) * SK + col] = __float2bfloat16(fmaxf(v, 0.f));
      }
  }
  __syncthreads();

  floatx4 acc2[RT][2];
  #pragma unroll
  for (int rt = 0; rt < RT; rt++)
    #pragma unroll
    for (int c = 0; c < 2; c++) acc2[rt][c] = (floatx4){0.f, 0.f, 0.f, 0.f};
  #pragma unroll
  for (int ks = 0; ks < 4; ks++) {
    short8 bfr0 = *(const short8*)(W2p + (((size_t)(wave * 2 + 0) * 4 + ks) * 64 + lane) * 8);
    short8 bfr1 = *(const short8*)(W2p + (((size_t)(wave * 2 + 1) * 4 + ks) * 64 + lane) * 8);
    #pragma unroll
    for (int rt = 0; rt < RT; rt++) {
      short8 a = *(const short8*)(&Hid[(rt * 16 + colq) * SK + ks * 32 + quad * 8]);
      acc2[rt][0] = __builtin_amdgcn_mfma_f32_16x16x32_bf16(a, bfr0, acc2[rt][0], 0, 0, 0);
      acc2[rt][1] = __builtin_amdgcn_mfma_f32_16x16x32_bf16(a, bfr1, acc2[rt][1], 0, 0, 0);
    }
  }
  #pragma unroll
  for (int c = 0; c < 2; c++) {
    int col = wave * 32 + c * 16 + colq;
    float bv = b2f(b2v[col]);
    #pragma unroll
    for (int rt = 0; rt < RT; rt++)
      #pragma unroll
      for (int r = 0; r < 4; r++) {
        int lrow = rt * 16 + quad * 4 + r;
        int grow = row0 + lrow;
        if (grow < M) {
          float v = acc2[rt][c][r] + bv;
          if constexpr (RES_PART >= 0)
            v += b2f(Zt[lrow * SK + RES_PART * 128 + col]);
          outp[(size_t)grow * HDIM + col] = __float2bfloat16(v);
        }
      }
  }
}

// ---------------------------------------------------------------- launcher
extern "C" void kernel_launch(void* const* d_in, const int* in_sizes, int n_in,
                              void* d_out, int out_size, void* d_ws, size_t ws_size,
                              hipStream_t stream) {
  const int* edge_index = (const int*)d_in[27];
  const int* node_types = (const int*)d_in[28];
  const int N = in_sizes[28];
  const int E = in_sizes[2] / 4;
  const int L = in_sizes[12] / HDIM;
  const int* srcI = edge_index;
  const int* dstI = edge_index + E;

  CanonDesc cd;
  int total = 0;
  for (int i = 0; i < NCANON; i++) { cd.src[i] = d_in[i]; cd.prefix[i] = total; total += in_sizes[i]; }
  cd.prefix[NCANON] = total;

  char* wsb = (char*)d_ws;
  size_t off = 0;
  auto alloc = [&](size_t bytes) -> void* {
    void* p = wsb + off;
    off += (bytes + 255) & ~(size_t)255;
    return p;
  };
  int*  flag      = (int*)alloc(256);
  bf16* arena     = (bf16*)alloc((size_t)total * 2);
  bf16* h_nodes   = (bf16*)alloc((size_t)N * HDIM * 2);
  bf16* h_edges   = (bf16*)alloc((size_t)E * HDIM * 2);
  bf16* m_node    = (bf16*)alloc((size_t)N * HDIM * 2);
  bf16* localb    = (bf16*)alloc((size_t)N * HDIM * 2);
  bf16* ysrcb     = (bf16*)alloc((size_t)N * HDIM * 2);
  bf16* ydstb     = (bf16*)alloc((size_t)N * HDIM * 2);
  bf16* canon_out = (bf16*)alloc((size_t)out_size * 2);
  int* counts     = (int*)alloc((size_t)N * 4);
  int* cursor     = (int*)alloc((size_t)N * 4);
  int* row_start  = (int*)alloc((size_t)(N + 1) * 4);
  int* bsum       = (int*)alloc(260 * 4);
  int* sortedE    = (int*)alloc((size_t)E * 4);
  int* srcS       = (int*)alloc((size_t)E * 4);
  int* dstS       = (int*)alloc((size_t)E * 4);
  int* bcntT      = (int*)alloc(512 * 4);
  int* boffT      = (int*)alloc(512 * 4);
  int* tsArr      = (int*)alloc(64);
  int* permT      = (int*)alloc((size_t)N * 4);
  bf16* eeW1p  = (bf16*)alloc(4096 * 2);
  bf16* eeW2p  = (bf16*)alloc(16384 * 2);
  bf16* encW1p = (bf16*)alloc(3 * 4096 * 2);
  bf16* encW2p = (bf16*)alloc(3 * 16384 * 2);
  bf16* decW1p = (bf16*)alloc(3 * 16384 * 2);
  bf16* decW2p = (bf16*)alloc(3 * 16384 * 2);
  bf16* euW1a  = (bf16*)alloc((size_t)L * 16384 * 2);
  bf16* euW1b  = (bf16*)alloc((size_t)L * 16384 * 2);
  bf16* euW1c  = (bf16*)alloc((size_t)L * 16384 * 2);
  bf16* euW2p  = (bf16*)alloc((size_t)L * 16384 * 2);
  bf16* nuW1p  = (bf16*)alloc((size_t)L * 32768 * 2);
  bf16* nuW2p  = (bf16*)alloc((size_t)L * 16384 * 2);
  bf16* fuW1p  = (bf16*)alloc((size_t)L * 16384 * 2);
  bf16* fuW2p  = (bf16*)alloc((size_t)L * 16384 * 2);

  const bf16* cX     = arena + cd.prefix[0];
  const bf16* cPE    = arena + cd.prefix[1];
  const bf16* cEA    = arena + cd.prefix[2];
  const bf16* cEncW1 = arena + cd.prefix[3];
  const bf16* cEncB1 = arena + cd.prefix[4];
  const bf16* cEncW2 = arena + cd.prefix[5];
  const bf16* cEncB2 = arena + cd.prefix[6];
  const bf16* cEeW1  = arena + cd.prefix[7];
  const bf16* cEeB1  = arena + cd.prefix[8];
  const bf16* cEeW2  = arena + cd.prefix[9];
  const bf16* cEeB2  = arena + cd.prefix[10];
  const bf16* cEuW1  = arena + cd.prefix[11];
  const bf16* cEuB1  = arena + cd.prefix[12];
  const bf16* cEuW2  = arena + cd.prefix[13];
  const bf16* cEuB2  = arena + cd.prefix[14];
  const bf16* cNuW1  = arena + cd.prefix[15];
  const bf16* cNuB1  = arena + cd.prefix[16];
  const bf16* cNuW2  = arena + cd.prefix[17];
  const bf16* cNuB2  = arena + cd.prefix[18];
  const bf16* cFuW1  = arena + cd.prefix[19];
  const bf16* cFuB1  = arena + cd.prefix[20];
  const bf16* cFuW2  = arena + cd.prefix[21];
  const bf16* cFuB2  = arena + cd.prefix[22];
  const bf16* cDecW1 = arena + cd.prefix[23];
  const bf16* cDecB1 = arena + cd.prefix[24];
  const bf16* cDecW2 = arena + cd.prefix[25];
  const bf16* cDecB2 = arena + cd.prefix[26];

  detect_kernel<<<1, 64, 0, stream>>>((const unsigned short*)d_in[0], flag);
  canon_kernel<<<(total + 255) / 256, 256, 0, stream>>>(cd, flag, arena, total);

  hipMemsetAsync(counts, 0, (size_t)N * 4, stream);
  hipMemsetAsync(cursor, 0, (size_t)N * 4, stream);

  PackJobs PJ;
  int nj = 0;
  PJ.j[nj++] = {cEeW1, eeW1p, 4, 1, 128};
  PJ.j[nj++] = {cEeW2, eeW2p, 128, 4, 128};
  for (int l = 0; l < L; l++) {
    const bf16* w1 = cEuW1 + (size_t)l * 384 * HDIM;
    PJ.j[nj++] = {w1,                 euW1a + (size_t)l * 16384, 128, 4, 128};
    PJ.j[nj++] = {w1 + 128 * HDIM,    euW1b + (size_t)l * 16384, 128, 4, 128};
    PJ.j[nj++] = {w1 + 256 * HDIM,    euW1c + (size_t)l * 16384, 128, 4, 128};
    PJ.j[nj++] = {cEuW2 + (size_t)l * HDIM * HDIM, euW2p + (size_t)l * 16384, 128, 4, 128};
    PJ.j[nj++] = {cNuW1 + (size_t)l * 256 * HDIM,  nuW1p + (size_t)l * 32768, 256, 8, 128};
    PJ.j[nj++] = {cNuW2 + (size_t)l * HDIM * HDIM, nuW2p + (size_t)l * 16384, 128, 4, 128};
    PJ.j[nj++] = {cFuW1 + (size_t)l * HDIM * HDIM, fuW1p + (size_t)l * 16384, 128, 4, 128};
    PJ.j[nj++] = {cFuW2 + (size_t)l * HDIM * HDIM, fuW2p + (size_t)l * 16384, 128, 4, 128};
  }
  for (int t = 0; t < 3; t++) {
    PJ.j[nj++] = {cEncW1 + (size_t)t * 14 * HDIM,   encW1p + (size_t)t * 4096, 14, 1, 128};
    PJ.j[nj++] = {cEncW2 + (size_t)t * HDIM * HDIM, encW2p + (size_t)t * 16384, 128, 4, 128};
    PJ.j[nj++] = {cDecW1 + (size_t)t * HDIM * HDIM, decW1p + (size_t)t * 16384, 128, 4, 128};
    PJ.j[nj++] = {cDecW2 + (size_t)t * HDIM * 4,    decW2p + (size_t)t * 16384, 128, 4, 4};
  }
  pack_all_kernel<<<dim3(16, nj), 256, 0, stream>>>(PJ);

  // CSR (dst-sorted edges)
  int nb = (N + 255) / 256;
  hist_kernel<<<(E + 255) / 256, 256, 0, stream>>>(dstI, counts, E);
  scan1_kernel<<<nb, 256, 0, stream>>>(counts, bsum, N);
  scan2_kernel<<<1, 64, 0, stream>>>(bsum, nb);
  scan3_kernel<<<nb, 256, 0, stream>>>(counts, bsum, row_start, N, nb);
  scatter_kernel<<<(E + 255) / 256, 256, 0, stream>>>(srcI, dstI, row_start, cursor,
                                                      sortedE, srcS, dstS, E);
  // type-sorted node permutation (atomic-free counting sort)
  tcount_kernel<<<nb, 256, 0, stream>>>(node_types, bcntT, N);
  tscan_kernel<<<1, 64, 0, stream>>>(bcntT, boffT, tsArr, nb, N);
  tscatter2_kernel<<<nb, 256, 0, stream>>>(node_types, boffT, permT, N);

  int ngrid64 = (N + 63) / 64;
  // typed encoder
  typed_kernel<1, false><<<dim3(ngrid64, 3), 256, 0, stream>>>(
      cX, cPE, permT, tsArr, encW1p, 4096, cEncB1, HDIM,
      encW2p, 16384, cEncB2, HDIM, h_nodes);

  int egrid32  = (E + 31) / 32;
  int egrid128 = (E + 127) / 128;
  int ngrid128 = (N + 127) / 128;

  // edge encoder -> h_edges (dst-sorted order via sortedE gather)
  mlp2_kernel<1, 1, -1, 128, 0, true><<<egrid128, 256, 0, stream>>>(
      cEA, sortedE, nullptr, eeW1p, cEeB1, eeW2p, cEeB2, h_edges, E);

  for (int l = 0; l < L; l++) {
    // per-node Y = h_nodes @ W1a / W1b
    ygemm_kernel<<<dim3(ngrid64, 2), 256, 0, stream>>>(
        h_nodes, euW1a + (size_t)l * 16384, euW1b + (size_t)l * 16384, ysrcb, ydstb, N);
    // edge update with ysum trick
    eu_kernel<32><<<egrid32, 256, 0, stream>>>(
        h_edges, ysrcb, ydstb, srcS, dstS,
        euW1c + (size_t)l * 16384, cEuB1 + l * HDIM,
        euW2p + (size_t)l * 16384, cEuB2 + l * HDIM, h_edges, E);
    aggregate_kernel<<<(N + 3) / 4, 256, 0, stream>>>(h_edges, row_start, m_node, N);
    mlp2_kernel<2, 8, 0, 64, 128, false><<<ngrid64, 256, 0, stream>>>(
        h_nodes, nullptr, m_node,
        nuW1p + (size_t)l * 32768, cNuB1 + l * HDIM,
        nuW2p + (size_t)l * 16384, cNuB2 + l * HDIM, localb, N);
    mlp2_kernel<1, 4, -1, 128, 0, false><<<ngrid128, 256, 0, stream>>>(
        localb, nullptr, nullptr,
        fuW1p + (size_t)l * 16384, cFuB1 + l * HDIM,
        fuW2p + (size_t)l * 16384, cFuB2 + l * HDIM, h_nodes, N);
  }

  // typed decoder
  typed_kernel<4, true><<<dim3(ngrid64, 3), 256, 0, stream>>>(
      h_nodes, nullptr, permT, tsArr, decW1p, 16384, cDecB1, HDIM,
      decW2p, 16384, cDecB2, 4, canon_out);
  emit_kernel<<<(out_size + 255) / 256, 256, 0, stream>>>(canon_out, flag, d_out, out_size);
  (void)n_in; (void)ws_size;
}

// Round 7
// 503.835 us; speedup vs baseline: 1.5816x; 1.0668x over previous
//
#include <hip/hip_runtime.h>
#include <hip/hip_bf16.h>

typedef __hip_bfloat16 bf16;
typedef __attribute__((ext_vector_type(8))) short short8;   // 8 bf16 frag
typedef __attribute__((ext_vector_type(4))) float floatx4;  // MFMA C/D frag

#define HDIM 128
#define NCANON 27

__device__ __forceinline__ float b2f(bf16 v) { return __bfloat162float(v); }
__device__ __forceinline__ float s2f(short s) {
  return __uint_as_float(((unsigned int)(unsigned short)s) << 16);
}
__device__ __forceinline__ short f2s(float f) {
  return (short)__bfloat16_as_ushort(__float2bfloat16(f));
}

// ------------------------------------------------- dtype detect (bf16 vs f32)
__global__ void detect_kernel(const unsigned short* __restrict__ xraw, int* __restrict__ flag) {
  int j = threadIdx.x;                      // 64 threads
  unsigned short u = xraw[2 * j];
  int e = (u >> 7) & 0xFF;
  int ok = (u == 0) || (e >= 100 && e <= 140);
  unsigned long long m = __ballot(ok);
  if (j == 0) flag[0] = (__popcll(m) >= 48) ? 1 : 0;   // 1 = bf16 storage
}

struct CanonDesc {
  const void* src[NCANON];
  int prefix[NCANON + 1];
};

__global__ void canon_kernel(CanonDesc d, const int* __restrict__ flag,
                             bf16* __restrict__ out, int total) {
  int t = blockIdx.x * 256 + threadIdx.x;
  if (t >= total) return;
  int ti = 0;
  while (d.prefix[ti + 1] <= t) ti++;
  int off = t - d.prefix[ti];
  if (flag[0]) out[t] = ((const bf16*)d.src[ti])[off];
  else         out[t] = __float2bfloat16(((const float*)d.src[ti])[off]);
}

__global__ void emit_kernel(const bf16* __restrict__ canon_out, const int* __restrict__ flag,
                            void* __restrict__ d_out, int n) {
  int t = blockIdx.x * 256 + threadIdx.x;
  if (t >= n) return;
  if (flag[0]) ((bf16*)d_out)[t] = canon_out[t];
  else         ((float*)d_out)[t] = __bfloat162float(canon_out[t]);
}

// ---------------------------------------------------------------- CSR build
__global__ void hist_kernel(const int* __restrict__ dst, int* __restrict__ cnt, int E) {
  int e = blockIdx.x * 256 + threadIdx.x;
  if (e < E) atomicAdd(&cnt[dst[e]], 1);
}

__global__ void scan1_kernel(const int* __restrict__ cnt, int* __restrict__ bsum, int n) {
  int tid = threadIdx.x, lane = tid & 63, wave = tid >> 6;
  int i = blockIdx.x * 256 + tid;
  int v = (i < n) ? cnt[i] : 0;
  #pragma unroll
  for (int d = 32; d; d >>= 1) v += __shfl_down(v, d);
  __shared__ int ws[4];
  if (lane == 0) ws[wave] = v;
  __syncthreads();
  if (tid == 0) bsum[blockIdx.x] = ws[0] + ws[1] + ws[2] + ws[3];
}

__global__ void scan2_kernel(int* __restrict__ bsum, int nb) {   // nb <= 128; 64 threads
  int lane = threadIdx.x;
  int a0 = (lane < nb) ? bsum[lane] : 0;
  int b0 = (64 + lane < nb) ? bsum[64 + lane] : 0;
  int a = a0, b = b0;
  #pragma unroll
  for (int d = 1; d < 64; d <<= 1) { int t = __shfl_up(a, d); if (lane >= d) a += t; }
  int totA = __shfl(a, 63);
  #pragma unroll
  for (int d = 1; d < 64; d <<= 1) { int t = __shfl_up(b, d); if (lane >= d) b += t; }
  int totB = __shfl(b, 63);
  if (lane < nb) bsum[lane] = a - a0;
  if (64 + lane < nb) bsum[64 + lane] = b - b0 + totA;
  if (lane == 0) bsum[nb] = totA + totB;
}

__global__ void scan3_kernel(const int* __restrict__ cnt, const int* __restrict__ bsum,
                             int* __restrict__ row_start, int n, int nb) {
  __shared__ int sh[256];
  int tid = threadIdx.x;
  int i = blockIdx.x * 256 + tid;
  int v = (i < n) ? cnt[i] : 0;
  sh[tid] = v;
  __syncthreads();
  #pragma unroll
  for (int off = 1; off < 256; off <<= 1) {
    int t = (tid >= off) ? sh[tid - off] : 0;
    __syncthreads();
    sh[tid] += t;
    __syncthreads();
  }
  if (i < n) row_start[i] = bsum[blockIdx.x] + sh[tid] - v;
  if (blockIdx.x == 0 && tid == 0) row_start[n] = bsum[nb];
}

__global__ void scatter_kernel(const int* __restrict__ src, const int* __restrict__ dst,
                               const int* __restrict__ row_start, int* __restrict__ cursor,
                               int* __restrict__ sortedE, int* __restrict__ srcS,
                               int* __restrict__ dstS, int E) {
  int e = blockIdx.x * 256 + threadIdx.x;
  if (e < E) {
    int d = dst[e];
    int pos = row_start[d] + atomicAdd(&cursor[d], 1);
    sortedE[pos] = e;
    srcS[pos] = src[e];
    dstS[pos] = d;
  }
}

// --------------------------------- type permutation: atomic-free counting sort
__global__ void tcount_kernel(const int* __restrict__ types, int* __restrict__ bcnt, int n) {
  int i = blockIdx.x * 256 + threadIdx.x;
  int lane = threadIdx.x & 63, wave = threadIdx.x >> 6;
  int t = (i < n) ? types[i] : -1;
  __shared__ int wc[4][3];
  unsigned long long m0 = __ballot(t == 0);
  unsigned long long m1 = __ballot(t == 1);
  unsigned long long m2 = __ballot(t == 2);
  if (lane == 0) {
    wc[wave][0] = __popcll(m0); wc[wave][1] = __popcll(m1); wc[wave][2] = __popcll(m2);
  }
  __syncthreads();
  if (threadIdx.x < 3)
    bcnt[blockIdx.x * 3 + threadIdx.x] =
        wc[0][threadIdx.x] + wc[1][threadIdx.x] + wc[2][threadIdx.x] + wc[3][threadIdx.x];
}

__global__ void tscan_kernel(const int* __restrict__ bcnt, int* __restrict__ boff,
                             int* __restrict__ ts, int nb, int n) {
  int lane = threadIdx.x;   // 64
  __shared__ int tots[3];
  for (int t = 0; t < 3; t++) {
    int a0 = (lane < nb) ? bcnt[lane * 3 + t] : 0;
    int b0 = (64 + lane < nb) ? bcnt[(64 + lane) * 3 + t] : 0;
    int a = a0, b = b0;
    #pragma unroll
    for (int d = 1; d < 64; d <<= 1) { int x = __shfl_up(a, d); if (lane >= d) a += x; }
    int totA = __shfl(a, 63);
    #pragma unroll
    for (int d = 1; d < 64; d <<= 1) { int x = __shfl_up(b, d); if (lane >= d) b += x; }
    int totB = __shfl(b, 63);
    if (lane < nb) boff[lane * 3 + t] = a - a0;
    if (64 + lane < nb) boff[(64 + lane) * 3 + t] = b - b0 + totA;
    if (lane == 0) tots[t] = totA + totB;
  }
  __syncthreads();
  int tot0 = tots[0], tot1 = tots[1];
  if (lane == 0) { ts[0] = 0; ts[1] = tot0; ts[2] = tot0 + tot1; ts[3] = n; }
  for (int idx = lane; idx < nb; idx += 64) {
    boff[idx * 3 + 1] += tot0;
    boff[idx * 3 + 2] += tot0 + tot1;
  }
}

__global__ void tscatter2_kernel(const int* __restrict__ types, const int* __restrict__ boff,
                                 int* __restrict__ perm, int n) {
  int i = blockIdx.x * 256 + threadIdx.x;
  int lane = threadIdx.x & 63, wave = threadIdx.x >> 6;
  int t = (i < n) ? types[i] : -1;
  __shared__ int wc[4][3];
  unsigned long long m0 = __ballot(t == 0);
  unsigned long long m1 = __ballot(t == 1);
  unsigned long long m2 = __ballot(t == 2);
  if (lane == 0) {
    wc[wave][0] = __popcll(m0); wc[wave][1] = __popcll(m1); wc[wave][2] = __popcll(m2);
  }
  __syncthreads();
  if (i >= n) return;
  unsigned long long mt = (t == 0) ? m0 : ((t == 1) ? m1 : m2);
  unsigned long long below = (lane == 0) ? 0ull : ((1ull << lane) - 1ull);
  int laneRank = __popcll(mt & below);
  int waveOff = 0;
  for (int w = 0; w < wave; w++) waveOff += wc[w][t];
  perm[boff[blockIdx.x * 3 + t] + waveOff + laneRank] = i;
}

// -------------------------------------------------- fused weight pre-pack (B-frag order)
struct PackJob { const bf16* src; bf16* dst; int Ksrc; int KS; int srcCols; };
struct PackJobs { PackJob j[40]; };

__global__ void pack_all_kernel(PackJobs J) {
  PackJob job = J.j[blockIdx.y];
  int idx = blockIdx.x * 256 + threadIdx.x;
  int total = 8 * job.KS * 64;
  if (idx >= total) return;
  int lane = idx & 63;
  int ks = (idx >> 6) % job.KS;
  int ct = idx / (64 * job.KS);
  bf16* o = job.dst + (size_t)idx * 8;
  int ncol = ct * 16 + (lane & 15);
  int kb = ks * 32 + ((lane >> 4) & 3) * 8;
  #pragma unroll
  for (int jj = 0; jj < 8; jj++) {
    int k = kb + jj;
    o[jj] = (k < job.Ksrc && ncol < job.srcCols)
              ? job.src[(size_t)k * job.srcCols + ncol] : __float2bfloat16(0.f);
  }
}

// -------------------------------------------------- single-GEMM node kernel (Y = X @ W)
__global__ void __launch_bounds__(256) ygemm_kernel(
    const bf16* __restrict__ X,
    const bf16* __restrict__ WpA, const bf16* __restrict__ WpB,
    bf16* __restrict__ outA, bf16* __restrict__ outB, int M) {
  const bf16* Wp = blockIdx.y ? WpB : WpA;
  bf16* outp = blockIdx.y ? outB : outA;
  constexpr int BM = 64, RT = 4, SK = 136;
  __shared__ bf16 Zt[BM * SK];
  const int tid = threadIdx.x;
  const int lane = tid & 63, wave = tid >> 6, colq = lane & 15, quad = lane >> 4;
  const int row0 = blockIdx.x * BM;
  {
    int row = tid >> 2, sub = tid & 3;
    int gr = row0 + row;
    bool ok = gr < M;
    #pragma unroll
    for (int j = 0; j < 4; j++) {
      int seg = j * 4 + sub;
      uint4 v = {0u, 0u, 0u, 0u};
      if (ok) v = *(const uint4*)(X + (size_t)gr * HDIM + seg * 8);
      *(uint4*)(&Zt[row * SK + seg * 8]) = v;
    }
  }
  __syncthreads();
  floatx4 acc[RT][2];
  #pragma unroll
  for (int rt = 0; rt < RT; rt++)
    #pragma unroll
    for (int c = 0; c < 2; c++) acc[rt][c] = (floatx4){0.f, 0.f, 0.f, 0.f};
  #pragma unroll
  for (int ks = 0; ks < 4; ks++) {
    short8 bfr0 = *(const short8*)(Wp + (((size_t)(wave * 2 + 0) * 4 + ks) * 64 + lane) * 8);
    short8 bfr1 = *(const short8*)(Wp + (((size_t)(wave * 2 + 1) * 4 + ks) * 64 + lane) * 8);
    #pragma unroll
    for (int rt = 0; rt < RT; rt++) {
      short8 a = *(const short8*)(&Zt[(rt * 16 + colq) * SK + ks * 32 + quad * 8]);
      acc[rt][0] = __builtin_amdgcn_mfma_f32_16x16x32_bf16(a, bfr0, acc[rt][0], 0, 0, 0);
      acc[rt][1] = __builtin_amdgcn_mfma_f32_16x16x32_bf16(a, bfr1, acc[rt][1], 0, 0, 0);
    }
  }
  #pragma unroll
  for (int c = 0; c < 2; c++) {
    int col = wave * 32 + c * 16 + colq;
    #pragma unroll
    for (int rt = 0; rt < RT; rt++)
      #pragma unroll
      for (int r = 0; r < 4; r++) {
        int grow = row0 + rt * 16 + quad * 4 + r;
        if (grow < M) outp[(size_t)grow * HDIM + col] = __float2bfloat16(acc[rt][c][r]);
      }
  }
}

// ----------------------- edge-update + fused dst-segment aggregation
// out = h_e_old + (ReLU(h_e @ W1c + ysum + b1) @ W2 + b2); m_node[dst] += out (f32)
// Zt part0 = ysum (becomes Hid in-place), part1 = h_e (becomes out in-place).
// Edges dst-sorted: per-block segmented column sums; boundary runs atomicAdd.
template<int BM>
__global__ void __launch_bounds__(256) eu_kernel(
    const bf16* __restrict__ he, const bf16* __restrict__ ysrc, const bf16* __restrict__ ydst,
    const int* __restrict__ srcS, const int* __restrict__ dstS,
    const bf16* __restrict__ W1p, const bf16* __restrict__ b1v,
    const bf16* __restrict__ W2p, const bf16* __restrict__ b2v,
    bf16* __restrict__ outp, float* __restrict__ mnode, int M) {
  constexpr int RT = BM / 16;
  constexpr int SK = 264;
  __shared__ bf16 Zt[BM * SK];
  __shared__ int dstLds[BM];
  const int tid = threadIdx.x;
  const int lane = tid & 63, wave = tid >> 6, colq = lane & 15, quad = lane >> 4;
  const int row0 = blockIdx.x * BM;
  constexpr int TPR = 256 / BM;
  {
    int row = tid / TPR, sub = tid % TPR;
    int gr = row0 + row;
    bool ok = gr < M;
    int g0 = ok ? srcS[gr] : 0;
    int g1 = ok ? dstS[gr] : 0;
    if (sub == 0) dstLds[row] = ok ? g1 : -1;
    #pragma unroll
    for (int j = 0; j < 32 / TPR; j++) {
      int c = j * TPR + sub;
      int part = c >> 4, seg = c & 15;
      if (part == 0) {
        short8 o = {0, 0, 0, 0, 0, 0, 0, 0};
        if (ok) {
          short8 a = *(const short8*)(ysrc + (size_t)g0 * HDIM + seg * 8);
          short8 b = *(const short8*)(ydst + (size_t)g1 * HDIM + seg * 8);
          #pragma unroll
          for (int k = 0; k < 8; k++) o[k] = f2s(s2f(a[k]) + s2f(b[k]));
        }
        *(short8*)(&Zt[row * SK + seg * 8]) = o;
      } else {
        uint4 v = {0u, 0u, 0u, 0u};
        if (ok) v = *(const uint4*)(he + (size_t)gr * HDIM + seg * 8);
        *(uint4*)(&Zt[row * SK + 128 + seg * 8]) = v;
      }
    }
  }
  __syncthreads();

  floatx4 acc[RT][2];
  #pragma unroll
  for (int rt = 0; rt < RT; rt++)
    #pragma unroll
    for (int c = 0; c < 2; c++) acc[rt][c] = (floatx4){0.f, 0.f, 0.f, 0.f};
  #pragma unroll
  for (int ks = 0; ks < 4; ks++) {
    short8 bfr0 = *(const short8*)(W1p + (((size_t)(wave * 2 + 0) * 4 + ks) * 64 + lane) * 8);
    short8 bfr1 = *(const short8*)(W1p + (((size_t)(wave * 2 + 1) * 4 + ks) * 64 + lane) * 8);
    #pragma unroll
    for (int rt = 0; rt < RT; rt++) {
      short8 a = *(const short8*)(&Zt[(rt * 16 + colq) * SK + 128 + ks * 32 + quad * 8]);
      acc[rt][0] = __builtin_amdgcn_mfma_f32_16x16x32_bf16(a, bfr0, acc[rt][0], 0, 0, 0);
      acc[rt][1] = __builtin_amdgcn_mfma_f32_16x16x32_bf16(a, bfr1, acc[rt][1], 0, 0, 0);
    }
  }
  // GEMM1 epilogue: Hid = ReLU(acc + b1 + ysum), written in place over part0
  #pragma unroll
  for (int c = 0; c < 2; c++) {
    int col = wave * 32 + c * 16 + colq;
    float bv = b2f(b1v[col]);
    #pragma unroll
    for (int rt = 0; rt < RT; rt++)
      #pragma unroll
      for (int r = 0; r < 4; r++) {
        int lrow = rt * 16 + quad * 4 + r;
        float v = acc[rt][c][r] + bv + b2f(Zt[lrow * SK + col]);
        Zt[lrow * SK + col] = __float2bfloat16(fmaxf(v, 0.f));
      }
  }
  __syncthreads();

  floatx4 acc2[RT][2];
  #pragma unroll
  for (int rt = 0; rt < RT; rt++)
    #pragma unroll
    for (int c = 0; c < 2; c++) acc2[rt][c] = (floatx4){0.f, 0.f, 0.f, 0.f};
  #pragma unroll
  for (int ks = 0; ks < 4; ks++) {
    short8 bfr0 = *(const short8*)(W2p + (((size_t)(wave * 2 + 0) * 4 + ks) * 64 + lane) * 8);
    short8 bfr1 = *(const short8*)(W2p + (((size_t)(wave * 2 + 1) * 4 + ks) * 64 + lane) * 8);
    #pragma unroll
    for (int rt = 0; rt < RT; rt++) {
      short8 a = *(const short8*)(&Zt[(rt * 16 + colq) * SK + ks * 32 + quad * 8]);
      acc2[rt][0] = __builtin_amdgcn_mfma_f32_16x16x32_bf16(a, bfr0, acc2[rt][0], 0, 0, 0);
      acc2[rt][1] = __builtin_amdgcn_mfma_f32_16x16x32_bf16(a, bfr1, acc2[rt][1], 0, 0, 0);
    }
  }
  // GEMM2 epilogue: out = acc2 + b2 + h_e(part1); store global AND back into part1
  #pragma unroll
  for (int c = 0; c < 2; c++) {
    int col = wave * 32 + c * 16 + colq;
    float bv = b2f(b2v[col]);
    #pragma unroll
    for (int rt = 0; rt < RT; rt++)
      #pragma unroll
      for (int r = 0; r < 4; r++) {
        int lrow = rt * 16 + quad * 4 + r;
        int grow = row0 + lrow;
        float v = acc2[rt][c][r] + bv + b2f(Zt[lrow * SK + 128 + col]);
        bf16 vb = __float2bfloat16(v);
        Zt[lrow * SK + 128 + col] = vb;        // per-lane owned slot (read above)
        if (grow < M) outp[(size_t)grow * HDIM + col] = vb;
      }
  }
  __syncthreads();

  // fused aggregation: segmented column sums over the block's dst-sorted rows
  if (tid < 128) {
    int col = tid;
    float s = 0.f;
    int runDst = dstLds[0];
    bool touchStart = true;
    for (int r = 0; r < BM; r++) {
      int d = dstLds[r];
      if (d != runDst) {
        if (runDst >= 0) {
          float* mp = &mnode[(size_t)runDst * HDIM + col];
          if (touchStart) atomicAdd(mp, s); else *mp = s;
        }
        runDst = d; s = 0.f; touchStart = false;
      }
      s += b2f(Zt[r * SK + 128 + col]);
    }
    if (runDst >= 0) atomicAdd(&mnode[(size_t)runDst * HDIM + col], s);  // touches end
  }
}

// ----------------------- fused node update + fusion MLP (nu + fu)
// local = h + ReLU([h||m]W1n + b1n)W2n + b2n ; h' = ReLU(local W1f + b1f)W2f + b2f
// Zt part0 = h (becomes local in place), part1 = m (becomes Hid/Hid2 in place).
__global__ void __launch_bounds__(256) node_kernel(
    const bf16* __restrict__ h_nodes, const float* __restrict__ mnode,
    const bf16* __restrict__ nuW1, const bf16* __restrict__ nuB1,
    const bf16* __restrict__ nuW2, const bf16* __restrict__ nuB2,
    const bf16* __restrict__ fuW1, const bf16* __restrict__ fuB1,
    const bf16* __restrict__ fuW2, const bf16* __restrict__ fuB2,
    bf16* __restrict__ outp, int M) {
  constexpr int BM = 64, RT = 4, SK = 264;
  __shared__ bf16 Zt[BM * SK];
  const int tid = threadIdx.x;
  const int lane = tid & 63, wave = tid >> 6, colq = lane & 15, quad = lane >> 4;
  const int row0 = blockIdx.x * BM;
  {
    int row = tid >> 2, sub = tid & 3;     // TPR = 4
    int gr = row0 + row;
    bool ok = gr < M;
    #pragma unroll
    for (int j = 0; j < 8; j++) {
      int c = j * 4 + sub;
      int part = c >> 4, seg = c & 15;
      if (part == 0) {
        uint4 v = {0u, 0u, 0u, 0u};
        if (ok) v = *(const uint4*)(h_nodes + (size_t)gr * HDIM + seg * 8);
        *(uint4*)(&Zt[row * SK + seg * 8]) = v;
      } else {
        short8 o = {0, 0, 0, 0, 0, 0, 0, 0};
        if (ok) {
          const float* mp = mnode + (size_t)gr * HDIM + seg * 8;
          #pragma unroll
          for (int k = 0; k < 8; k++) o[k] = f2s(mp[k]);
        }
        *(short8*)(&Zt[row * SK + 128 + seg * 8]) = o;
      }
    }
  }
  __syncthreads();

  floatx4 acc[RT][2];
  // ---- nu GEMM1: K=256 over [h || m]
  #pragma unroll
  for (int rt = 0; rt < RT; rt++)
    #pragma unroll
    for (int c = 0; c < 2; c++) acc[rt][c] = (floatx4){0.f, 0.f, 0.f, 0.f};
  #pragma unroll
  for (int ks = 0; ks < 8; ks++) {
    short8 bfr0 = *(const short8*)(nuW1 + (((size_t)(wave * 2 + 0) * 8 + ks) * 64 + lane) * 8);
    short8 bfr1 = *(const short8*)(nuW1 + (((size_t)(wave * 2 + 1) * 8 + ks) * 64 + lane) * 8);
    #pragma unroll
    for (int rt = 0; rt < RT; rt++) {
      short8 a = *(const short8*)(&Zt[(rt * 16 + colq) * SK + ks * 32 + quad * 8]);
      acc[rt][0] = __builtin_amdgcn_mfma_f32_16x16x32_bf16(a, bfr0, acc[rt][0], 0, 0, 0);
      acc[rt][1] = __builtin_amdgcn_mfma_f32_16x16x32_bf16(a, bfr1, acc[rt][1], 0, 0, 0);
    }
  }
  __syncthreads();   // all GEMM1 reads of part1 done before Hid overwrites it
  #pragma unroll
  for (int c = 0; c < 2; c++) {
    int col = wave * 32 + c * 16 + colq;
    float bv = b2f(nuB1[col]);
    #pragma unroll
    for (int rt = 0; rt < RT; rt++)
      #pragma unroll
      for (int r = 0; r < 4; r++)
        Zt[(rt * 16 + quad * 4 + r) * SK + 128 + col] =
            __float2bfloat16(fmaxf(acc[rt][c][r] + bv, 0.f));
  }
  __syncthreads();

  // ---- nu GEMM2: local = h(part0) + HidW2 + b2 -> written into part0
  #pragma unroll
  for (int rt = 0; rt < RT; rt++)
    #pragma unroll
    for (int c = 0; c < 2; c++) acc[rt][c] = (floatx4){0.f, 0.f, 0.f, 0.f};
  #pragma unroll
  for (int ks = 0; ks < 4; ks++) {
    short8 bfr0 = *(const short8*)(nuW2 + (((size_t)(wave * 2 + 0) * 4 + ks) * 64 + lane) * 8);
    short8 bfr1 = *(const short8*)(nuW2 + (((size_t)(wave * 2 + 1) * 4 + ks) * 64 + lane) * 8);
    #pragma unroll
    for (int rt = 0; rt < RT; rt++) {
      short8 a = *(const short8*)(&Zt[(rt * 16 + colq) * SK + 128 + ks * 32 + quad * 8]);
      acc[rt][0] = __builtin_amdgcn_mfma_f32_16x16x32_bf16(a, bfr0, acc[rt][0], 0, 0, 0);
      acc[rt][1] = __builtin_amdgcn_mfma_f32_16x16x32_bf16(a, bfr1, acc[rt][1], 0, 0, 0);
    }
  }
  #pragma unroll
  for (int c = 0; c < 2; c++) {
    int col = wave * 32 + c * 16 + colq;
    float bv = b2f(nuB2[col]);
    #pragma unroll
    for (int rt = 0; rt < RT; rt++)
      #pragma unroll
      for (int r = 0; r < 4; r++) {
        int lrow = rt * 16 + quad * 4 + r;
        float v = acc[rt][c][r] + bv + b2f(Zt[lrow * SK + col]);   // + h residual
        Zt[lrow * SK + col] = __float2bfloat16(v);                 // local, in place
      }
  }
  __syncthreads();

  // ---- fu GEMM1: Hid2 = ReLU(local W1f + b1f) -> part1
  #pragma unroll
  for (int rt = 0; rt < RT; rt++)
    #pragma unroll
    for (int c = 0; c < 2; c++) acc[rt][c] = (floatx4){0.f, 0.f, 0.f, 0.f};
  #pragma unroll
  for (int ks = 0; ks < 4; ks++) {
    short8 bfr0 = *(const short8*)(fuW1 + (((size_t)(wave * 2 + 0) * 4 + ks) * 64 + lane) * 8);
    short8 bfr1 = *(const short8*)(fuW1 + (((size_t)(wave * 2 + 1) * 4 + ks) * 64 + lane) * 8);
    #pragma unroll
    for (int rt = 0; rt < RT; rt++) {
      short8 a = *(const short8*)(&Zt[(rt * 16 + colq) * SK + ks * 32 + quad * 8]);
      acc[rt][0] = __builtin_amdgcn_mfma_f32_16x16x32_bf16(a, bfr0, acc[rt][0], 0, 0, 0);
      acc[rt][1] = __builtin_amdgcn_mfma_f32_16x16x32_bf16(a, bfr1, acc[rt][1], 0, 0, 0);
    }
  }
  #pragma unroll
  for (int c = 0; c < 2; c++) {
    int col = wave * 32 + c * 16 + colq;
    float bv = b2f(fuB1[col]);
    #pragma unroll
    for (int rt = 0; rt < RT; rt++)
      #pragma unroll
      for (int r = 0; r < 4; r++)
        Zt[(rt * 16 + quad * 4 + r) * SK + 128 + col] =
            __float2bfloat16(fmaxf(acc[rt][c][r] + bv, 0.f));
  }
  __syncthreads();

  // ---- fu GEMM2: h' = Hid2 W2f + b2f -> global
  #pragma unroll
  for (int rt = 0; rt < RT; rt++)
    #pragma unroll
    for (int c = 0; c < 2; c++) acc[rt][c] = (floatx4){0.f, 0.f, 0.f, 0.f};
  #pragma unroll
  for (int ks = 0; ks < 4; ks++) {
    short8 bfr0 = *(const short8*)(fuW2 + (((size_t)(wave * 2 + 0) * 4 + ks) * 64 + lane) * 8);
    short8 bfr1 = *(const short8*)(fuW2 + (((size_t)(wave * 2 + 1) * 4 + ks) * 64 + lane) * 8);
    #pragma unroll
    for (int rt = 0; rt < RT; rt++) {
      short8 a = *(const short8*)(&Zt[(rt * 16 + colq) * SK + 128 + ks * 32 + quad * 8]);
      acc[rt][0] = __builtin_amdgcn_mfma_f32_16x16x32_bf16(a, bfr0, acc[rt][0], 0, 0, 0);
      acc[rt][1] = __builtin_amdgcn_mfma_f32_16x16x32_bf16(a, bfr1, acc[rt][1], 0, 0, 0);
    }
  }
  #pragma unroll
  for (int c = 0; c < 2; c++) {
    int col = wave * 32 + c * 16 + colq;
    float bv = b2f(fuB2[col]);
    #pragma unroll
    for (int rt = 0; rt < RT; rt++)
      #pragma unroll
      for (int r = 0; r < 4; r++) {
        int grow = row0 + rt * 16 + quad * 4 + r;
        if (grow < M) outp[(size_t)grow * HDIM + col] = __float2bfloat16(acc[rt][c][r] + bv);
      }
  }
}

// -------------------------------------------------- typed enc/dec (type-sorted MFMA)
template<int KS1, bool DEC>
__global__ void __launch_bounds__(256) typed_kernel(
    const bf16* __restrict__ in0, const bf16* __restrict__ in1,
    const int* __restrict__ perm, const int* __restrict__ ts,
    const bf16* __restrict__ W1p, int w1s, const bf16* __restrict__ b1v, int b1s,
    const bf16* __restrict__ W2p, int w2s, const bf16* __restrict__ b2v, int b2s,
    bf16* __restrict__ outp) {
  constexpr int BM = 64, RT = 4;
  constexpr int SK = KS1 * 32 + 8;
  constexpr int HS = 136;
  int t = blockIdx.y;
  int rs = ts[t], re = ts[t + 1];
  int row0 = rs + blockIdx.x * BM;
  if (row0 >= re) return;
  __shared__ bf16 Zt[BM * SK];
  __shared__ bf16 Hid[BM * HS];
  __shared__ int gIdx[BM];
  const int tid = threadIdx.x;
  const int lane = tid & 63, wave = tid >> 6, colq = lane & 15, quad = lane >> 4;
  for (int i = tid; i < BM; i += 256) gIdx[i] = (row0 + i < re) ? perm[row0 + i] : -1;
  __syncthreads();
  if (DEC) {
    int row = tid >> 2, sub = tid & 3;
    int g = gIdx[row];
    #pragma unroll
    for (int j = 0; j < 4; j++) {
      int seg = j * 4 + sub;
      uint4 v = {0u, 0u, 0u, 0u};
      if (g >= 0) v = *(const uint4*)(in0 + (size_t)g * HDIM + seg * 8);
      *(uint4*)(&Zt[row * SK + seg * 8]) = v;
    }
  } else {
    for (int i = tid; i < BM * 32; i += 256) {
      int row = i >> 5, k = i & 31;
      int g = gIdx[row];
      bf16 v = __float2bfloat16(0.f);
      if (g >= 0 && k < 14) v = (k < 6) ? in0[(size_t)g * 6 + k] : in1[(size_t)g * 8 + (k - 6)];
      Zt[row * SK + k] = v;
    }
  }
  __syncthreads();

  const bf16* W1t = W1p + (size_t)t * w1s;
  const bf16* W2t = W2p + (size_t)t * w2s;
  floatx4 acc[RT][2];
  #pragma unroll
  for (int rt = 0; rt < RT; rt++)
    #pragma unroll
    for (int c = 0; c < 2; c++) acc[rt][c] = (floatx4){0.f, 0.f, 0.f, 0.f};
  #pragma unroll
  for (int ks = 0; ks < KS1; ks++) {
    short8 bfr0 = *(const short8*)(W1t + (((size_t)(wave * 2 + 0) * KS1 + ks) * 64 + lane) * 8);
    short8 bfr1 = *(const short8*)(W1t + (((size_t)(wave * 2 + 1) * KS1 + ks) * 64 + lane) * 8);
    #pragma unroll
    for (int rt = 0; rt < RT; rt++) {
      short8 a = *(const short8*)(&Zt[(rt * 16 + colq) * SK + ks * 32 + quad * 8]);
      acc[rt][0] = __builtin_amdgcn_mfma_f32_16x16x32_bf16(a, bfr0, acc[rt][0], 0, 0, 0);
      acc[rt][1] = __builtin_amdgcn_mfma_f32_16x16x32_bf16(a, bfr1, acc[rt][1], 0, 0, 0);
    }
  }
  #pragma unroll
  for (int c = 0; c < 2; c++) {
    int col = wave * 32 + c * 16 + colq;
    float bv = b2f(b1v[t * b1s + col]);
    #pragma unroll
    for (int rt = 0; rt < RT; rt++)
      #pragma unroll
      for (int r = 0; r < 4; r++) {
        float v = acc[rt][c][r] + bv;
        Hid[(rt * 16 + quad * 4 + r) * HS + col] = __float2bfloat16(fmaxf(v, 0.f));
      }
  }
  __syncthreads();

  floatx4 acc2[RT][2];
  #pragma unroll
  for (int rt = 0; rt < RT; rt++)
    #pragma unroll
    for (int c = 0; c < 2; c++) acc2[rt][c] = (floatx4){0.f, 0.f, 0.f, 0.f};
  #pragma unroll
  for (int ks = 0; ks < 4; ks++) {
    short8 bfr0 = *(const short8*)(W2t + (((size_t)(wave * 2 + 0) * 4 + ks) * 64 + lane) * 8);
    short8 bfr1 = *(const short8*)(W2t + (((size_t)(wave * 2 + 1) * 4 + ks) * 64 + lane) * 8);
    #pragma unroll
    for (int rt = 0; rt < RT; rt++) {
      short8 a = *(const short8*)(&Hid[(rt * 16 + colq) * HS + ks * 32 + quad * 8]);
      acc2[rt][0] = __builtin_amdgcn_mfma_f32_16x16x32_bf16(a, bfr0, acc2[rt][0], 0, 0, 0);
      acc2[rt][1] = __builtin_amdgcn_mfma_f32_16x16x32_bf16(a, bfr1, acc2[rt][1], 0, 0, 0);
    }
  }
  if (DEC) {
    if (wave == 0 && colq < 4) {
      float bv = b2f(b2v[t * b2s + colq]);
      #pragma unroll
      for (int rt = 0; rt < RT; rt++)
        #pragma unroll
        for (int r = 0; r < 4; r++) {
          int g = gIdx[rt * 16 + quad * 4 + r];
          if (g >= 0) outp[(size_t)g * 4 + colq] = __float2bfloat16(acc2[rt][0][r] + bv);
        }
    }
  } else {
    #pragma unroll
    for (int c = 0; c < 2; c++) {
      int col = wave * 32 + c * 16 + colq;
      float bv = b2f(b2v[t * b2s + col]);
      #pragma unroll
      for (int rt = 0; rt < RT; rt++)
        #pragma unroll
        for (int r = 0; r < 4; r++) {
          int g = gIdx[rt * 16 + quad * 4 + r];
          if (g >= 0) outp[(size_t)g * HDIM + col] = __float2bfloat16(acc2[rt][c][r] + bv);
        }
    }
  }
}

// -------------------------------------------------- edge-encoder MLP (attr4 path)
template<int BM>
__global__ void __launch_bounds__(256) ee_kernel(
    const bf16* __restrict__ p0, const int* __restrict__ idx0,
    const bf16* __restrict__ W1p, const bf16* __restrict__ b1v,
    const bf16* __restrict__ W2p, const bf16* __restrict__ b2v,
    bf16* __restrict__ outp, int M) {
  constexpr int RT = BM / 16;
  constexpr int SK = 136;
  __shared__ bf16 Zt[BM * SK];
  const int tid = threadIdx.x;
  const int lane = tid & 63, wave = tid >> 6, colq = lane & 15, quad = lane >> 4;
  const int row0 = blockIdx.x * BM;

  for (int i = tid; i < BM * 4; i += 256) {
    int row = i >> 2, seg = i & 3;
    int gr = row0 + row;
    uint4 val = {0u, 0u, 0u, 0u};
    if (seg == 0 && gr < M) {
      int g = idx0 ? idx0[gr] : gr;
      uint2 v = *(const uint2*)(p0 + (size_t)g * 4);
      val.x = v.x; val.y = v.y;
    }
    *(uint4*)(&Zt[row * SK + seg * 8]) = val;
  }
  __syncthreads();

  floatx4 acc[RT][2];
  #pragma unroll
  for (int rt = 0; rt < RT; rt++)
    #pragma unroll
    for (int c = 0; c < 2; c++) acc[rt][c] = (floatx4){0.f, 0.f, 0.f, 0.f};
  {
    short8 bfr0 = *(const short8*)(W1p + (((size_t)(wave * 2 + 0)) * 64 + lane) * 8);
    short8 bfr1 = *(const short8*)(W1p + (((size_t)(wave * 2 + 1)) * 64 + lane) * 8);
    #pragma unroll
    for (int rt = 0; rt < RT; rt++) {
      short8 a = *(const short8*)(&Zt[(rt * 16 + colq) * SK + quad * 8]);
      acc[rt][0] = __builtin_amdgcn_mfma_f32_16x16x32_bf16(a, bfr0, acc[rt][0], 0, 0, 0);
      acc[rt][1] = __builtin_amdgcn_mfma_f32_16x16x32_bf16(a, bfr1, acc[rt][1], 0, 0, 0);
    }
  }
  __syncthreads();
  #pragma unroll
  for (int c = 0; c < 2; c++) {
    int col = wave * 32 + c * 16 + colq;
    float bv = b2f(b1v[col]);
    #pragma unroll
    for (int rt = 0; rt < RT; rt++)
      #pragma unroll
      for (int r = 0; r < 4; r++)
        Zt[(rt * 16 + quad * 4 + r) * SK + col] =
            __float2bfloat16(fmaxf(acc[rt][c][r] + bv, 0.f));
  }
  __syncthreads();

  floatx4 acc2[RT][2];
  #pragma unroll
  for (int rt = 0; rt < RT; rt++)
    #pragma unroll
    for (int c = 0; c < 2; c++) acc2[rt][c] = (floatx4){0.f, 0.f, 0.f, 0.f};
  #pragma unroll
  for (int ks = 0; ks < 4; ks++) {
    short8 bfr0 = *(const short8*)(W2p + (((size_t)(wave * 2 + 0) * 4 + ks) * 64 + lane) * 8);
    short8 bfr1 = *(const short8*)(W2p + (((size_t)(wave * 2 + 1) * 4 + ks) * 64 + lane) * 8);
    #pragma unroll
    for (int rt = 0; rt < RT; rt++) {
      short8 a = *(const short8*)(&Zt[(rt * 16 + colq) * SK + ks * 32 + quad * 8]);
      acc2[rt][0] = __builtin_amdgcn_mfma_f32_16x16x32_bf16(a, bfr0, acc2[rt][0], 0, 0, 0);
      acc2[rt][1] = __builtin_amdgcn_mfma_f32_16x16x32_bf16(a, bfr1, acc2[rt][1], 0, 0, 0);
    }
  }
  #pragma unroll
  for (int c = 0; c < 2; c++) {
    int col = wave * 32 + c * 16 + colq;
    float bv = b2f(b2v[col]);
    #pragma unroll
    for (int rt = 0; rt < RT; rt++)
      #pragma unroll
      for (int r = 0; r < 4; r++) {
        int grow = row0 + rt * 16 + quad * 4 + r;
        if (grow < M)
          outp[(size_t)grow * HDIM + col] = __float2bfloat16(acc2[rt][c][r] + bv);
      }
  }
}

// ---------------------------------------------------------------- launcher
extern "C" void kernel_launch(void* const* d_in, const int* in_sizes, int n_in,
                              void* d_out, int out_size, void* d_ws, size_t ws_size,
                              hipStream_t stream) {
  const int* edge_index = (const int*)d_in[27];
  const int* node_types = (const int*)d_in[28];
  const int N = in_sizes[28];
  const int E = in_sizes[2] / 4;
  const int L = in_sizes[12] / HDIM;
  const int* srcI = edge_index;
  const int* dstI = edge_index + E;

  CanonDesc cd;
  int total = 0;
  for (int i = 0; i < NCANON; i++) { cd.src[i] = d_in[i]; cd.prefix[i] = total; total += in_sizes[i]; }
  cd.prefix[NCANON] = total;

  char* wsb = (char*)d_ws;
  size_t off = 0;
  auto alloc = [&](size_t bytes) -> void* {
    void* p = wsb + off;
    off += (bytes + 255) & ~(size_t)255;
    return p;
  };
  int*  flag      = (int*)alloc(256);
  bf16* arena     = (bf16*)alloc((size_t)total * 2);
  bf16* h_nodes   = (bf16*)alloc((size_t)N * HDIM * 2);
  bf16* h_edges   = (bf16*)alloc((size_t)E * HDIM * 2);
  float* m_node   = (float*)alloc((size_t)N * HDIM * 4);
  bf16* ysrcb     = (bf16*)alloc((size_t)N * HDIM * 2);
  bf16* ydstb     = (bf16*)alloc((size_t)N * HDIM * 2);
  bf16* canon_out = (bf16*)alloc((size_t)out_size * 2);
  int* counts     = (int*)alloc((size_t)N * 4);
  int* cursor     = (int*)alloc((size_t)N * 4);
  int* row_start  = (int*)alloc((size_t)(N + 1) * 4);
  int* bsum       = (int*)alloc(260 * 4);
  int* sortedE    = (int*)alloc((size_t)E * 4);
  int* srcS       = (int*)alloc((size_t)E * 4);
  int* dstS       = (int*)alloc((size_t)E * 4);
  int* bcntT      = (int*)alloc(512 * 4);
  int* boffT      = (int*)alloc(512 * 4);
  int* tsArr      = (int*)alloc(64);
  int* permT      = (int*)alloc((size_t)N * 4);
  bf16* eeW1p  = (bf16*)alloc(4096 * 2);
  bf16* eeW2p  = (bf16*)alloc(16384 * 2);
  bf16* encW1p = (bf16*)alloc(3 * 4096 * 2);
  bf16* encW2p = (bf16*)alloc(3 * 16384 * 2);
  bf16* decW1p = (bf16*)alloc(3 * 16384 * 2);
  bf16* decW2p = (bf16*)alloc(3 * 16384 * 2);
  bf16* euW1a  = (bf16*)alloc((size_t)L * 16384 * 2);
  bf16* euW1b  = (bf16*)alloc((size_t)L * 16384 * 2);
  bf16* euW1c  = (bf16*)alloc((size_t)L * 16384 * 2);
  bf16* euW2p  = (bf16*)alloc((size_t)L * 16384 * 2);
  bf16* nuW1p  = (bf16*)alloc((size_t)L * 32768 * 2);
  bf16* nuW2p  = (bf16*)alloc((size_t)L * 16384 * 2);
  bf16* fuW1p  = (bf16*)alloc((size_t)L * 16384 * 2);
  bf16* fuW2p  = (bf16*)alloc((size_t)L * 16384 * 2);

  const bf16* cX     = arena + cd.prefix[0];
  const bf16* cPE    = arena + cd.prefix[1];
  const bf16* cEA    = arena + cd.prefix[2];
  const bf16* cEncW1 = arena + cd.prefix[3];
  const bf16* cEncB1 = arena + cd.prefix[4];
  const bf16* cEncW2 = arena + cd.prefix[5];
  const bf16* cEncB2 = arena + cd.prefix[6];
  const bf16* cEeW1  = arena + cd.prefix[7];
  const bf16* cEeB1  = arena + cd.prefix[8];
  const bf16* cEeW2  = arena + cd.prefix[9];
  const bf16* cEeB2  = arena + cd.prefix[10];
  const bf16* cEuW1  = arena + cd.prefix[11];
  const bf16* cEuB1  = arena + cd.prefix[12];
  const bf16* cEuW2  = arena + cd.prefix[13];
  const bf16* cEuB2  = arena + cd.prefix[14];
  const bf16* cNuW1  = arena + cd.prefix[15];
  const bf16* cNuB1  = arena + cd.prefix[16];
  const bf16* cNuW2  = arena + cd.prefix[17];
  const bf16* cNuB2  = arena + cd.prefix[18];
  const bf16* cFuW1  = arena + cd.prefix[19];
  const bf16* cFuB1  = arena + cd.prefix[20];
  const bf16* cFuW2  = arena + cd.prefix[21];
  const bf16* cFuB2  = arena + cd.prefix[22];
  const bf16* cDecW1 = arena + cd.prefix[23];
  const bf16* cDecB1 = arena + cd.prefix[24];
  const bf16* cDecW2 = arena + cd.prefix[25];
  const bf16* cDecB2 = arena + cd.prefix[26];

  detect_kernel<<<1, 64, 0, stream>>>((const unsigned short*)d_in[0], flag);
  canon_kernel<<<(total + 255) / 256, 256, 0, stream>>>(cd, flag, arena, total);

  hipMemsetAsync(counts, 0, (size_t)N * 4, stream);
  hipMemsetAsync(cursor, 0, (size_t)N * 4, stream);

  PackJobs PJ;
  int nj = 0;
  PJ.j[nj++] = {cEeW1, eeW1p, 4, 1, 128};
  PJ.j[nj++] = {cEeW2, eeW2p, 128, 4, 128};
  for (int l = 0; l < L; l++) {
    const bf16* w1 = cEuW1 + (size_t)l * 384 * HDIM;
    PJ.j[nj++] = {w1,                 euW1a + (size_t)l * 16384, 128, 4, 128};
    PJ.j[nj++] = {w1 + 128 * HDIM,    euW1b + (size_t)l * 16384, 128, 4, 128};
    PJ.j[nj++] = {w1 + 256 * HDIM,    euW1c + (size_t)l * 16384, 128, 4, 128};
    PJ.j[nj++] = {cEuW2 + (size_t)l * HDIM * HDIM, euW2p + (size_t)l * 16384, 128, 4, 128};
    PJ.j[nj++] = {cNuW1 + (size_t)l * 256 * HDIM,  nuW1p + (size_t)l * 32768, 256, 8, 128};
    PJ.j[nj++] = {cNuW2 + (size_t)l * HDIM * HDIM, nuW2p + (size_t)l * 16384, 128, 4, 128};
    PJ.j[nj++] = {cFuW1 + (size_t)l * HDIM * HDIM, fuW1p + (size_t)l * 16384, 128, 4, 128};
    PJ.j[nj++] = {cFuW2 + (size_t)l * HDIM * HDIM, fuW2p + (size_t)l * 16384, 128, 4, 128};
  }
  for (int t = 0; t < 3; t++) {
    PJ.j[nj++] = {cEncW1 + (size_t)t * 14 * HDIM,   encW1p + (size_t)t * 4096, 14, 1, 128};
    PJ.j[nj++] = {cEncW2 + (size_t)t * HDIM * HDIM, encW2p + (size_t)t * 16384, 128, 4, 128};
    PJ.j[nj++] = {cDecW1 + (size_t)t * HDIM * HDIM, decW1p + (size_t)t * 16384, 128, 4, 128};
    PJ.j[nj++] = {cDecW2 + (size_t)t * HDIM * 4,    decW2p + (size_t)t * 16384, 128, 4, 4};
  }
  pack_all_kernel<<<dim3(16, nj), 256, 0, stream>>>(PJ);

  // CSR (dst-sorted edges)
  int nb = (N + 255) / 256;
  hist_kernel<<<(E + 255) / 256, 256, 0, stream>>>(dstI, counts, E);
  scan1_kernel<<<nb, 256, 0, stream>>>(counts, bsum, N);
  scan2_kernel<<<1, 64, 0, stream>>>(bsum, nb);
  scan3_kernel<<<nb, 256, 0, stream>>>(counts, bsum, row_start, N, nb);
  scatter_kernel<<<(E + 255) / 256, 256, 0, stream>>>(srcI, dstI, row_start, cursor,
                                                      sortedE, srcS, dstS, E);
  // type-sorted node permutation (atomic-free counting sort)
  tcount_kernel<<<nb, 256, 0, stream>>>(node_types, bcntT, N);
  tscan_kernel<<<1, 64, 0, stream>>>(bcntT, boffT, tsArr, nb, N);
  tscatter2_kernel<<<nb, 256, 0, stream>>>(node_types, boffT, permT, N);

  int ngrid64 = (N + 63) / 64;
  typed_kernel<1, false><<<dim3(ngrid64, 3), 256, 0, stream>>>(
      cX, cPE, permT, tsArr, encW1p, 4096, cEncB1, HDIM,
      encW2p, 16384, cEncB2, HDIM, h_nodes);

  int egrid32  = (E + 31) / 32;
  int egrid128 = (E + 127) / 128;

  // edge encoder -> h_edges (dst-sorted order via sortedE gather)
  ee_kernel<128><<<egrid128, 256, 0, stream>>>(
      cEA, sortedE, eeW1p, cEeB1, eeW2p, cEeB2, h_edges, E);

  for (int l = 0; l < L; l++) {
    hipMemsetAsync(m_node, 0, (size_t)N * HDIM * 4, stream);
    ygemm_kernel<<<dim3(ngrid64, 2), 256, 0, stream>>>(
        h_nodes, euW1a + (size_t)l * 16384, euW1b + (size_t)l * 16384, ysrcb, ydstb, N);
    eu_kernel<32><<<egrid32, 256, 0, stream>>>(
        h_edges, ysrcb, ydstb, srcS, dstS,
        euW1c + (size_t)l * 16384, cEuB1 + l * HDIM,
        euW2p + (size_t)l * 16384, cEuB2 + l * HDIM, h_edges, m_node, E);
    node_kernel<<<ngrid64, 256, 0, stream>>>(
        h_nodes, m_node,
        nuW1p + (size_t)l * 32768, cNuB1 + l * HDIM,
        nuW2p + (size_t)l * 16384, cNuB2 + l * HDIM,
        fuW1p + (size_t)l * 16384, cFuB1 + l * HDIM,
        fuW2p + (size_t)l * 16384, cFuB2 + l * HDIM, h_nodes, N);
  }

  typed_kernel<4, true><<<dim3(ngrid64, 3), 256, 0, stream>>>(
      h_nodes, nullptr, permT, tsArr, decW1p, 16384, cDecB1, HDIM,
      decW2p, 16384, cDecB2, 4, canon_out);
  emit_kernel<<<(out_size + 255) / 256, 256, 0, stream>>>(canon_out, flag, d_out, out_size);
  (void)n_in; (void)ws_size;
}